// Round 6
// baseline (761.468 us; speedup 1.0000x reference)
//
#include <hip/hip_runtime.h>
#include <hip/hip_bf16.h>

typedef unsigned short u16;
typedef unsigned char u8;
typedef short bf16x8 __attribute__((ext_vector_type(8)));
typedef float f32x4 __attribute__((ext_vector_type(4)));
typedef float f32x2 __attribute__((ext_vector_type(2)));

#define NN 100000
#define EE 3200000
#define BUCKET 128
static constexpr float COEF = 0.17677669529663687f; // 1/sqrt(32)

__device__ __forceinline__ u16 f2b(float f) {
    unsigned u = __float_as_uint(f);
    unsigned r = (u + 0x7fffu + ((u >> 16) & 1u)) >> 16;
    return (u16)r;
}

#define B2LO(w) __uint_as_float((w) << 16)
#define B2HI(w) __uint_as_float((w) & 0xffff0000u)

#define GLDS16(gp, lp) __builtin_amdgcn_global_load_lds( \
    (const __attribute__((address_space(1))) void*)(gp), \
    (__attribute__((address_space(3))) void*)(lp), 16, 0, 0)

// ---------- conversions ----------
__global__ __launch_bounds__(256) void cvt_x_kernel(const float* __restrict__ in,
                                                    u16* __restrict__ out, int n4) {
    int i = blockIdx.x * 256 + threadIdx.x;
    if (i >= n4) return;
    float4 v = ((const float4*)in)[i];
    ushort4 o;
    o.x = f2b(v.x); o.y = f2b(v.y); o.z = f2b(v.z); o.w = f2b(v.w);
    ((ushort4*)out)[i] = o;
}

__global__ __launch_bounds__(256) void transpose_bf16_kernel(const float* __restrict__ in,
                                                             u16* __restrict__ out, int R, int C) {
    int idx = blockIdx.x * 256 + threadIdx.x;
    if (idx >= R * C) return;
    int r = idx / C, c = idx - r * C;
    out[(size_t)c * R + r] = f2b(in[idx]);
}

// ---------- edge bucketing (replaces hist+scan+scatter) ----------
__global__ __launch_bounds__(256) void edge_bucket_kernel(const int* __restrict__ src,
                                                          const int* __restrict__ dst,
                                                          int* __restrict__ cnt,
                                                          int* __restrict__ esrc) {
    int e = blockIdx.x * 256 + threadIdx.x;
    int d = dst[e];
    int pos = atomicAdd(&cnt[d], 1);
    esrc[(size_t)d * BUCKET + pos] = src[e];
}

// ---------- per-node attention: 1 wave per node; lane = (head, edge_slot) ----------
// h = lane>>3 (8 heads), slot = lane&7 (8 edge slots per iteration).
// Each lane computes the FULL 32-dim dot for its (edge, head).
// K: [node][256] bf16 (512B/row). V: [node][256] fp8 e4m3 (256B/row).
// Private online softmax per lane (defer-max thr=4); one butterfly merge per node.
// Q and msg may alias (Q[node] fully read into regs before msg[node] written).
__global__ __launch_bounds__(256) void attn_kernel(
    const u16* Q, const u16* __restrict__ K, const u8* __restrict__ V,
    const int* __restrict__ cnt, const int* __restrict__ esrc,
    u16* msg) {
    int node = blockIdx.x * 4 + (threadIdx.x >> 6);
    int lane = threadIdx.x & 63;
    int h = lane >> 3;
    int slot = lane & 7;
    int r0 = node * BUCKET;
    int r1 = r0 + cnt[node];

    float q[32];
    {
        const uint4* qp = (const uint4*)(Q + (size_t)node * 256 + h * 32);
#pragma unroll
        for (int i = 0; i < 4; ++i) {
            uint4 wv = qp[i];
            q[i * 8 + 0] = B2LO(wv.x) * COEF; q[i * 8 + 1] = B2HI(wv.x) * COEF;
            q[i * 8 + 2] = B2LO(wv.y) * COEF; q[i * 8 + 3] = B2HI(wv.y) * COEF;
            q[i * 8 + 4] = B2LO(wv.z) * COEF; q[i * 8 + 5] = B2HI(wv.z) * COEF;
            q[i * 8 + 6] = B2LO(wv.w) * COEF; q[i * 8 + 7] = B2HI(wv.w) * COEF;
        }
    }

    float m = -3.0e38f, denom = 0.0f;
    float acc[32];
#pragma unroll
    for (int i = 0; i < 32; ++i) acc[i] = 0.0f;

#define DOT2(w, i0) d += q[i0] * B2LO(w) + q[(i0) + 1] * B2HI(w)
#define ACC4(u, i0) { f32x2 lo = __builtin_amdgcn_cvt_pk_f32_fp8(u, false); \
                      f32x2 hi = __builtin_amdgcn_cvt_pk_f32_fp8(u, true);  \
                      acc[i0]     = __builtin_fmaf(ex, lo[0], acc[i0]);     \
                      acc[(i0)+1] = __builtin_fmaf(ex, lo[1], acc[(i0)+1]); \
                      acc[(i0)+2] = __builtin_fmaf(ex, hi[0], acc[(i0)+2]); \
                      acc[(i0)+3] = __builtin_fmaf(ex, hi[1], acc[(i0)+3]); }

    for (int base = r0; base < r1; base += 8) {
        int myj = base + slot;
        bool valid = myj < r1;
        int s = valid ? esrc[myj] : 0;      // exec-masked load; s=0 rows are cached+unused
        const uint4* kp = (const uint4*)(K + (size_t)s * 256 + h * 32);
        const uint4* vp = (const uint4*)(V + (size_t)s * 256 + h * 32);
        uint4 k0 = kp[0], k1 = kp[1], k2 = kp[2], k3 = kp[3];
        uint4 va = vp[0], vb = vp[1];       // 32 fp8 values

        float d = 0.0f;
        DOT2(k0.x, 0);  DOT2(k0.y, 2);  DOT2(k0.z, 4);  DOT2(k0.w, 6);
        DOT2(k1.x, 8);  DOT2(k1.y, 10); DOT2(k1.z, 12); DOT2(k1.w, 14);
        DOT2(k2.x, 16); DOT2(k2.y, 18); DOT2(k2.z, 20); DOT2(k2.w, 22);
        DOT2(k3.x, 24); DOT2(k3.y, 26); DOT2(k3.z, 28); DOT2(k3.w, 30);
        if (!valid) d = -3.0e38f;

        if (d > m + 4.0f) {                 // defer-max: rescale only on big growth
            float scale = __expf(m - d);
            m = d;
            denom *= scale;
#pragma unroll
            for (int i = 0; i < 32; ++i) acc[i] *= scale;
        }
        float ex = valid ? __expf(d - m) : 0.0f;   // bounded by e^4
        denom += ex;
        ACC4(va.x, 0);  ACC4(va.y, 4);  ACC4(va.z, 8);  ACC4(va.w, 12);
        ACC4(vb.x, 16); ACC4(vb.y, 20); ACC4(vb.z, 24); ACC4(vb.w, 28);
    }

    // ---- per-node merge across the 8 slots ----
    float mg = fmaxf(m, __shfl_xor(m, 1));
    mg = fmaxf(mg, __shfl_xor(mg, 2));
    mg = fmaxf(mg, __shfl_xor(mg, 4));
    float f = __expf(m - mg);
    float dn = denom * f;
    dn += __shfl_xor(dn, 1);
    dn += __shfl_xor(dn, 2);
    dn += __shfl_xor(dn, 4);
#pragma unroll
    for (int i = 0; i < 32; ++i) acc[i] *= f;

    float t16[16];
#pragma unroll
    for (int i = 0; i < 16; ++i) {
        float send = (slot & 1) ? acc[i] : acc[i + 16];
        float recv = __shfl_xor(send, 1);
        t16[i] = ((slot & 1) ? acc[i + 16] : acc[i]) + recv;
    }
    float t8[8];
#pragma unroll
    for (int i = 0; i < 8; ++i) {
        float send = (slot & 2) ? t16[i] : t16[i + 8];
        float recv = __shfl_xor(send, 2);
        t8[i] = ((slot & 2) ? t16[i + 8] : t16[i]) + recv;
    }
    float t4[4];
#pragma unroll
    for (int i = 0; i < 4; ++i) {
        float send = (slot & 4) ? t8[i] : t8[i + 4];
        float recv = __shfl_xor(send, 4);
        t4[i] = ((slot & 4) ? t8[i + 4] : t8[i]) + recv;
    }
    int dimbase = ((slot & 1) << 4) | ((slot & 2) << 2) | (slot & 4);

    float inv = 1.0f / fmaxf(dn, 1e-20f);
    ushort4 o;
    o.x = f2b(t4[0] * inv); o.y = f2b(t4[1] * inv);
    o.z = f2b(t4[2] * inv); o.w = f2b(t4[3] * inv);
    *(ushort4*)(msg + (size_t)node * 256 + h * 32 + dimbase) = o;
}

// ---------- bf16 MFMA GEMM, BK=64, XOR-swizzled LDS ----------
// C(M x Ntot) = A(M x Ktot) * Bt(Ntot x Ktot)^T + bias
// MODE 0: fp32 out. MODE 1: Q,K bf16 + V fp8, de-interleaved.
// A row stride fixed 256; k<splitK reads A else A2 (virtual concat).
template <int MODE>
__global__ __launch_bounds__(256) void gemm_bt_kernel(
    const u16* __restrict__ A, const u16* __restrict__ A2, int splitK,
    const u16* __restrict__ Bt, const float* __restrict__ bias,
    int M, int Ntot, int Ktot, int ntiles_n,
    float* __restrict__ outF, u16* __restrict__ outQ, u16* __restrict__ outK,
    u8* __restrict__ outV) {
    __shared__ u16 As[128 * 64];
    __shared__ u16 Bs[128 * 64];
    const int tid = threadIdx.x;
    const int lane = tid & 63, wave = tid >> 6;
    const int wm = wave >> 1, wn = wave & 1;
    const int bm = blockIdx.x / ntiles_n, bn = blockIdx.x % ntiles_n;
    const int brow = bm * 128, bcol = bn * 128;

    f32x4 acc[4][4] = {};

    for (int k0 = 0; k0 < Ktot; k0 += 64) {
        const u16* Ab = (k0 < splitK) ? (A + k0) : (A2 + (k0 - splitK));
#pragma unroll
        for (int it = 0; it < 4; ++it) {
            int chunk = it * 256 + tid;          // 0..1023
            int row = chunk >> 3;                // 0..127
            int cg = chunk & 7;                  // 16B column-group
            int gcg = cg ^ (row & 7);            // inverse-swizzled global source
            int ga = brow + row; if (ga > M - 1) ga = M - 1;
            GLDS16(Ab + (size_t)ga * 256 + gcg * 8, As + (it * 256 + wave * 64) * 8);
            GLDS16(Bt + (size_t)(bcol + row) * Ktot + k0 + gcg * 8,
                   Bs + (it * 256 + wave * 64) * 8);
        }
        __syncthreads();
        const int kg = lane >> 4, rI = lane & 15, rx = lane & 7;
#pragma unroll
        for (int ks = 0; ks < 2; ++ks) {
            bf16x8 a[4], b[4];
#pragma unroll
            for (int m = 0; m < 4; ++m)
                a[m] = *(const bf16x8*)(As + (wm * 64 + m * 16 + rI) * 64 +
                                        (((ks * 4 + kg) ^ rx) * 8));
#pragma unroll
            for (int n = 0; n < 4; ++n)
                b[n] = *(const bf16x8*)(Bs + (wn * 64 + n * 16 + rI) * 64 +
                                        (((ks * 4 + kg) ^ rx) * 8));
#pragma unroll
            for (int m = 0; m < 4; ++m)
#pragma unroll
                for (int n = 0; n < 4; ++n)
                    acc[m][n] = __builtin_amdgcn_mfma_f32_16x16x32_bf16(a[m], b[n], acc[m][n], 0, 0, 0);
        }
        __syncthreads();
    }

#pragma unroll
    for (int m = 0; m < 4; ++m) {
        int growb = brow + wm * 64 + m * 16 + (lane >> 4) * 4;
#pragma unroll
        for (int n = 0; n < 4; ++n) {
            int gcol = bcol + wn * 64 + n * 16 + (lane & 15);
            float bi = bias[gcol];
#pragma unroll
            for (int r = 0; r < 4; ++r) {
                int grow = growb + r;
                if (grow >= M) continue;
                float c = acc[m][n][r] + bi;
                if (MODE == 0) {
                    outF[(size_t)grow * Ntot + gcol] = c;
                } else {
                    int hh = gcol / 96;
                    int rr = gcol - hh * 96;
                    int sel = rr >> 5;
                    int cc = hh * 32 + (rr & 31);
                    if (sel == 0)
                        outQ[(size_t)grow * 256 + cc] = f2b(c);
                    else if (sel == 1)
                        outK[(size_t)grow * 256 + cc] = f2b(c);
                    else {
                        unsigned pv = __builtin_amdgcn_cvt_pk_fp8_f32(c, c, 0, false);
                        outV[(size_t)grow * 256 + cc] = (u8)(pv & 0xff);
                    }
                }
            }
        }
    }
}

extern "C" void kernel_launch(void* const* d_in, const int* in_sizes, int n_in,
                              void* d_out, int out_size, void* d_ws, size_t ws_size,
                              hipStream_t stream) {
    const float* x = (const float*)d_in[0];
    const float* W_qkv = (const float*)d_in[1];
    const float* b_qkv = (const float*)d_in[2];
    const float* W_out = (const float*)d_in[3];
    const float* b_out = (const float*)d_in[4];
    const int* src = (const int*)d_in[5];
    const int* dst = (const int*)d_in[6];
    float* out = (float*)d_out;

    char* w = (char*)d_ws;
    size_t off = 0;
    auto alloc = [&](size_t bytes) -> char* {
        char* p = w + off;
        off += (bytes + 255) & ~(size_t)255;
        return p;
    };
    u16* xb = (u16*)alloc((size_t)NN * 256 * 2);
    u16* WbT = (u16*)alloc((size_t)768 * 256 * 2);
    u16* WoT = (u16*)alloc((size_t)256 * 512 * 2);
    u16* Qb = (u16*)alloc((size_t)NN * 256 * 2);
    u16* Kb = (u16*)alloc((size_t)NN * 256 * 2);
    u8* Vf8 = (u8*)alloc((size_t)NN * 256);
    u16* msg = Qb;  // alias: attn reads Q[node] fully into regs before writing msg[node]
    int* cnt = (int*)alloc((size_t)NN * 4);
    int* esrc = (int*)alloc((size_t)NN * BUCKET * 4);
    // total workspace ~ 232 MB

    hipMemsetAsync(cnt, 0, (size_t)NN * 4, stream);

    cvt_x_kernel<<<25000, 256, 0, stream>>>(x, xb, NN * 256 / 4);
    transpose_bf16_kernel<<<(256 * 768 + 255) / 256, 256, 0, stream>>>(W_qkv, WbT, 256, 768);
    transpose_bf16_kernel<<<(512 * 256 + 255) / 256, 256, 0, stream>>>(W_out, WoT, 512, 256);

    edge_bucket_kernel<<<EE / 256, 256, 0, stream>>>(src, dst, cnt, esrc);

    // QKV = xb @ W_qkv + b_qkv  -> Q,K bf16 + V fp8
    gemm_bt_kernel<1><<<782 * 6, 256, 0, stream>>>(xb, xb, 256, WbT, b_qkv, NN, 768, 256, 6,
                                                   nullptr, Qb, Kb, Vf8);

    attn_kernel<<<NN / 4, 256, 0, stream>>>(Qb, Kb, Vf8, cnt, esrc, msg);

    // out = [xb | msg] @ W_out + b_out  (fp32 out)
    gemm_bt_kernel<0><<<782 * 2, 256, 0, stream>>>(xb, msg, 256, WoT, b_out, NN, 256, 512, 2,
                                                   out, nullptr, nullptr, nullptr);
}

// Round 7
// 706.827 us; speedup vs baseline: 1.0773x; 1.0773x over previous
//
#include <hip/hip_runtime.h>
#include <hip/hip_bf16.h>

typedef unsigned short u16;
typedef unsigned char u8;
typedef short bf16x8 __attribute__((ext_vector_type(8)));
typedef float f32x4 __attribute__((ext_vector_type(4)));
typedef float f32x2 __attribute__((ext_vector_type(2)));

#define NN 100000
#define EE 3200000
#define BUCKET 128
static constexpr float COEF = 0.17677669529663687f; // 1/sqrt(32)

__device__ __forceinline__ u16 f2b(float f) {
    unsigned u = __float_as_uint(f);
    unsigned r = (u + 0x7fffu + ((u >> 16) & 1u)) >> 16;
    return (u16)r;
}

#define B2LO(w) __uint_as_float((w) << 16)
#define B2HI(w) __uint_as_float((w) & 0xffff0000u)

#define GLDS16(gp, lp) __builtin_amdgcn_global_load_lds( \
    (const __attribute__((address_space(1))) void*)(gp), \
    (__attribute__((address_space(3))) void*)(lp), 16, 0, 0)

// ---------- conversions ----------
__global__ __launch_bounds__(256) void cvt_x_kernel(const float* __restrict__ in,
                                                    u16* __restrict__ out, int n4) {
    int i = blockIdx.x * 256 + threadIdx.x;
    if (i >= n4) return;
    float4 v = ((const float4*)in)[i];
    ushort4 o;
    o.x = f2b(v.x); o.y = f2b(v.y); o.z = f2b(v.z); o.w = f2b(v.w);
    ((ushort4*)out)[i] = o;
}

__global__ __launch_bounds__(256) void transpose_bf16_kernel(const float* __restrict__ in,
                                                             u16* __restrict__ out, int R, int C) {
    int idx = blockIdx.x * 256 + threadIdx.x;
    if (idx >= R * C) return;
    int r = idx / C, c = idx - r * C;
    out[(size_t)c * R + r] = f2b(in[idx]);
}

// ---------- edge bucketing (4 edges/thread) ----------
__global__ __launch_bounds__(256) void edge_bucket_kernel(const int* __restrict__ src,
                                                          const int* __restrict__ dst,
                                                          int* __restrict__ cnt,
                                                          int* __restrict__ esrc) {
    int e4 = blockIdx.x * 256 + threadIdx.x;
    int4 d = ((const int4*)dst)[e4];
    int4 s = ((const int4*)src)[e4];
    int p0 = atomicAdd(&cnt[d.x], 1);
    esrc[(size_t)d.x * BUCKET + p0] = s.x;
    int p1 = atomicAdd(&cnt[d.y], 1);
    esrc[(size_t)d.y * BUCKET + p1] = s.y;
    int p2 = atomicAdd(&cnt[d.z], 1);
    esrc[(size_t)d.z * BUCKET + p2] = s.z;
    int p3 = atomicAdd(&cnt[d.w], 1);
    esrc[(size_t)d.w * BUCKET + p3] = s.w;
}

// ---------- per-node attention: 1 wave per node; lane = (head, edge_slot) ----------
// h = lane>>3 (8 heads), slot = lane&7 (8 edge slots per iteration).
// Each lane computes the FULL 32-dim dot for its (edge, head).
// KV8: [node][512] bytes fp8 e4m3 — K in bytes 0..255 (dim=byte), V in 256..511.
// Private online softmax per lane (defer-max thr=4); one butterfly merge per node.
// Q and msg may alias (Q[node] fully read into regs before msg[node] written).
__global__ __launch_bounds__(256) void attn_kernel(
    const u16* Q, const u8* __restrict__ KV8,
    const int* __restrict__ cnt, const int* __restrict__ esrc,
    u16* msg) {
    int node = blockIdx.x * 4 + (threadIdx.x >> 6);
    int lane = threadIdx.x & 63;
    int h = lane >> 3;
    int slot = lane & 7;
    int r0 = node * BUCKET;
    int r1 = r0 + cnt[node];

    float q[32];
    {
        const uint4* qp = (const uint4*)(Q + (size_t)node * 256 + h * 32);
#pragma unroll
        for (int i = 0; i < 4; ++i) {
            uint4 wv = qp[i];
            q[i * 8 + 0] = B2LO(wv.x) * COEF; q[i * 8 + 1] = B2HI(wv.x) * COEF;
            q[i * 8 + 2] = B2LO(wv.y) * COEF; q[i * 8 + 3] = B2HI(wv.y) * COEF;
            q[i * 8 + 4] = B2LO(wv.z) * COEF; q[i * 8 + 5] = B2HI(wv.z) * COEF;
            q[i * 8 + 6] = B2LO(wv.w) * COEF; q[i * 8 + 7] = B2HI(wv.w) * COEF;
        }
    }

    float m = -3.0e38f, denom = 0.0f;
    float acc[32];
#pragma unroll
    for (int i = 0; i < 32; ++i) acc[i] = 0.0f;

// 4 fp8 values in dword u -> dot with q[i0..i0+3]
#define DOT4F8(u, i0) { f32x2 lo = __builtin_amdgcn_cvt_pk_f32_fp8(u, false); \
                        f32x2 hi = __builtin_amdgcn_cvt_pk_f32_fp8(u, true);  \
                        d += q[i0] * lo[0] + q[(i0)+1] * lo[1];               \
                        d += q[(i0)+2] * hi[0] + q[(i0)+3] * hi[1]; }
#define ACC4(u, i0) { f32x2 lo = __builtin_amdgcn_cvt_pk_f32_fp8(u, false); \
                      f32x2 hi = __builtin_amdgcn_cvt_pk_f32_fp8(u, true);  \
                      acc[i0]     = __builtin_fmaf(ex, lo[0], acc[i0]);     \
                      acc[(i0)+1] = __builtin_fmaf(ex, lo[1], acc[(i0)+1]); \
                      acc[(i0)+2] = __builtin_fmaf(ex, hi[0], acc[(i0)+2]); \
                      acc[(i0)+3] = __builtin_fmaf(ex, hi[1], acc[(i0)+3]); }

    for (int base = r0; base < r1; base += 8) {
        int myj = base + slot;
        bool valid = myj < r1;
        int s = valid ? esrc[myj] : 0;      // exec-masked load; s=0 rows cached+unused
        const uint4* kp = (const uint4*)(KV8 + (size_t)s * 512 + h * 32);
        uint4 ka = kp[0], kb = kp[1];       // 32 fp8 K values
        uint4 va = kp[16], vb = kp[17];     // +256B: 32 fp8 V values

        float d = 0.0f;
        DOT4F8(ka.x, 0);  DOT4F8(ka.y, 4);  DOT4F8(ka.z, 8);  DOT4F8(ka.w, 12);
        DOT4F8(kb.x, 16); DOT4F8(kb.y, 20); DOT4F8(kb.z, 24); DOT4F8(kb.w, 28);
        if (!valid) d = -3.0e38f;

        if (d > m + 4.0f) {                 // defer-max: rescale only on big growth
            float scale = __expf(m - d);
            m = d;
            denom *= scale;
#pragma unroll
            for (int i = 0; i < 32; ++i) acc[i] *= scale;
        }
        float ex = valid ? __expf(d - m) : 0.0f;   // bounded by e^4
        denom += ex;
        ACC4(va.x, 0);  ACC4(va.y, 4);  ACC4(va.z, 8);  ACC4(va.w, 12);
        ACC4(vb.x, 16); ACC4(vb.y, 20); ACC4(vb.z, 24); ACC4(vb.w, 28);
    }

    // ---- per-node merge across the 8 slots ----
    float mg = fmaxf(m, __shfl_xor(m, 1));
    mg = fmaxf(mg, __shfl_xor(mg, 2));
    mg = fmaxf(mg, __shfl_xor(mg, 4));
    float f = __expf(m - mg);
    float dn = denom * f;
    dn += __shfl_xor(dn, 1);
    dn += __shfl_xor(dn, 2);
    dn += __shfl_xor(dn, 4);
#pragma unroll
    for (int i = 0; i < 32; ++i) acc[i] *= f;

    float t16[16];
#pragma unroll
    for (int i = 0; i < 16; ++i) {
        float send = (slot & 1) ? acc[i] : acc[i + 16];
        float recv = __shfl_xor(send, 1);
        t16[i] = ((slot & 1) ? acc[i + 16] : acc[i]) + recv;
    }
    float t8[8];
#pragma unroll
    for (int i = 0; i < 8; ++i) {
        float send = (slot & 2) ? t16[i] : t16[i + 8];
        float recv = __shfl_xor(send, 2);
        t8[i] = ((slot & 2) ? t16[i + 8] : t16[i]) + recv;
    }
    float t4[4];
#pragma unroll
    for (int i = 0; i < 4; ++i) {
        float send = (slot & 4) ? t8[i] : t8[i + 4];
        float recv = __shfl_xor(send, 4);
        t4[i] = ((slot & 4) ? t8[i + 4] : t8[i]) + recv;
    }
    int dimbase = ((slot & 1) << 4) | ((slot & 2) << 2) | (slot & 4);

    float inv = 1.0f / fmaxf(dn, 1e-20f);
    ushort4 o;
    o.x = f2b(t4[0] * inv); o.y = f2b(t4[1] * inv);
    o.z = f2b(t4[2] * inv); o.w = f2b(t4[3] * inv);
    *(ushort4*)(msg + (size_t)node * 256 + h * 32 + dimbase) = o;
}

// ---------- bf16 MFMA GEMM, BK=64, XOR-swizzled LDS ----------
// C(M x Ntot) = A(M x Ktot) * Bt(Ntot x Ktot)^T + bias
// MODE 0: fp32 out. MODE 1: Q bf16 + fused KV8 fp8 rows.
// A row stride fixed 256; k<splitK reads A else A2 (virtual concat).
template <int MODE>
__global__ __launch_bounds__(256) void gemm_bt_kernel(
    const u16* __restrict__ A, const u16* __restrict__ A2, int splitK,
    const u16* __restrict__ Bt, const float* __restrict__ bias,
    int M, int Ntot, int Ktot, int ntiles_n,
    float* __restrict__ outF, u16* __restrict__ outQ, u8* __restrict__ outKV) {
    __shared__ u16 As[128 * 64];
    __shared__ u16 Bs[128 * 64];
    const int tid = threadIdx.x;
    const int lane = tid & 63, wave = tid >> 6;
    const int wm = wave >> 1, wn = wave & 1;
    const int bm = blockIdx.x / ntiles_n, bn = blockIdx.x % ntiles_n;
    const int brow = bm * 128, bcol = bn * 128;

    f32x4 acc[4][4] = {};

    for (int k0 = 0; k0 < Ktot; k0 += 64) {
        const u16* Ab = (k0 < splitK) ? (A + k0) : (A2 + (k0 - splitK));
#pragma unroll
        for (int it = 0; it < 4; ++it) {
            int chunk = it * 256 + tid;          // 0..1023
            int row = chunk >> 3;                // 0..127
            int cg = chunk & 7;                  // 16B column-group
            int gcg = cg ^ (row & 7);            // inverse-swizzled global source
            int ga = brow + row; if (ga > M - 1) ga = M - 1;
            GLDS16(Ab + (size_t)ga * 256 + gcg * 8, As + (it * 256 + wave * 64) * 8);
            GLDS16(Bt + (size_t)(bcol + row) * Ktot + k0 + gcg * 8,
                   Bs + (it * 256 + wave * 64) * 8);
        }
        __syncthreads();
        const int kg = lane >> 4, rI = lane & 15, rx = lane & 7;
#pragma unroll
        for (int ks = 0; ks < 2; ++ks) {
            bf16x8 a[4], b[4];
#pragma unroll
            for (int m = 0; m < 4; ++m)
                a[m] = *(const bf16x8*)(As + (wm * 64 + m * 16 + rI) * 64 +
                                        (((ks * 4 + kg) ^ rx) * 8));
#pragma unroll
            for (int n = 0; n < 4; ++n)
                b[n] = *(const bf16x8*)(Bs + (wn * 64 + n * 16 + rI) * 64 +
                                        (((ks * 4 + kg) ^ rx) * 8));
#pragma unroll
            for (int m = 0; m < 4; ++m)
#pragma unroll
                for (int n = 0; n < 4; ++n)
                    acc[m][n] = __builtin_amdgcn_mfma_f32_16x16x32_bf16(a[m], b[n], acc[m][n], 0, 0, 0);
        }
        __syncthreads();
    }

#pragma unroll
    for (int m = 0; m < 4; ++m) {
        int growb = brow + wm * 64 + m * 16 + (lane >> 4) * 4;
#pragma unroll
        for (int n = 0; n < 4; ++n) {
            int gcol = bcol + wn * 64 + n * 16 + (lane & 15);
            float bi = bias[gcol];
#pragma unroll
            for (int r = 0; r < 4; ++r) {
                int grow = growb + r;
                if (grow >= M) continue;
                float c = acc[m][n][r] + bi;
                if (MODE == 0) {
                    outF[(size_t)grow * Ntot + gcol] = c;
                } else {
                    int hh = gcol / 96;
                    int rr = gcol - hh * 96;
                    int sel = rr >> 5;
                    int cc = hh * 32 + (rr & 31);
                    if (sel == 0) {
                        outQ[(size_t)grow * 256 + cc] = f2b(c);
                    } else {
                        unsigned pv = __builtin_amdgcn_cvt_pk_fp8_f32(c, c, 0, false);
                        outKV[(size_t)grow * 512 + (sel - 1) * 256 + cc] = (u8)(pv & 0xff);
                    }
                }
            }
        }
    }
}

extern "C" void kernel_launch(void* const* d_in, const int* in_sizes, int n_in,
                              void* d_out, int out_size, void* d_ws, size_t ws_size,
                              hipStream_t stream) {
    const float* x = (const float*)d_in[0];
    const float* W_qkv = (const float*)d_in[1];
    const float* b_qkv = (const float*)d_in[2];
    const float* W_out = (const float*)d_in[3];
    const float* b_out = (const float*)d_in[4];
    const int* src = (const int*)d_in[5];
    const int* dst = (const int*)d_in[6];
    float* out = (float*)d_out;

    char* w = (char*)d_ws;
    size_t off = 0;
    auto alloc = [&](size_t bytes) -> char* {
        char* p = w + off;
        off += (bytes + 255) & ~(size_t)255;
        return p;
    };
    u16* xb = (u16*)alloc((size_t)NN * 256 * 2);
    u16* WbT = (u16*)alloc((size_t)768 * 256 * 2);
    u16* WoT = (u16*)alloc((size_t)256 * 512 * 2);
    u16* Qb = (u16*)alloc((size_t)NN * 256 * 2);
    u8* KV8 = (u8*)alloc((size_t)NN * 512);
    u16* msg = Qb;  // alias: attn reads Q[node] fully into regs before writing msg[node]
    int* cnt = (int*)alloc((size_t)NN * 4);
    int* esrc = (int*)alloc((size_t)NN * BUCKET * 4);
    // total workspace ~ 206 MB

    hipMemsetAsync(cnt, 0, (size_t)NN * 4, stream);

    cvt_x_kernel<<<25000, 256, 0, stream>>>(x, xb, NN * 256 / 4);
    transpose_bf16_kernel<<<(256 * 768 + 255) / 256, 256, 0, stream>>>(W_qkv, WbT, 256, 768);
    transpose_bf16_kernel<<<(512 * 256 + 255) / 256, 256, 0, stream>>>(W_out, WoT, 512, 256);

    edge_bucket_kernel<<<EE / 1024, 256, 0, stream>>>(src, dst, cnt, esrc);

    // QKV = xb @ W_qkv + b_qkv  -> Q bf16 + fused KV8 fp8
    gemm_bt_kernel<1><<<782 * 6, 256, 0, stream>>>(xb, xb, 256, WbT, b_qkv, NN, 768, 256, 6,
                                                   nullptr, Qb, KV8);

    attn_kernel<<<NN / 4, 256, 0, stream>>>(Qb, KV8, cnt, esrc, msg);

    // out = [xb | msg] @ W_out + b_out  (fp32 out)
    gemm_bt_kernel<0><<<782 * 2, 256, 0, stream>>>(xb, msg, 256, WoT, b_out, NN, 256, 512, 2,
                                                   out, nullptr, nullptr);
}

// Round 8
// 671.484 us; speedup vs baseline: 1.1340x; 1.0526x over previous
//
#include <hip/hip_runtime.h>
#include <hip/hip_bf16.h>

typedef unsigned short u16;
typedef unsigned char u8;
typedef short bf16x8 __attribute__((ext_vector_type(8)));
typedef float f32x4 __attribute__((ext_vector_type(4)));
typedef float f32x2 __attribute__((ext_vector_type(2)));

#define NN 100000
#define EE 3200000
#define BUCKET 128
#define NB 782          // coarse buckets: node>>7, 128 nodes each
#define SUBCAP 768      // capacity per (coarse, xcd) sub-bucket; mean ~512, 11 sigma margin
static constexpr float COEF = 0.17677669529663687f; // 1/sqrt(32)

__device__ __forceinline__ u16 f2b(float f) {
    unsigned u = __float_as_uint(f);
    unsigned r = (u + 0x7fffu + ((u >> 16) & 1u)) >> 16;
    return (u16)r;
}

#define B2LO(w) __uint_as_float((w) << 16)
#define B2HI(w) __uint_as_float((w) & 0xffff0000u)

#define GLDS16(gp, lp) __builtin_amdgcn_global_load_lds( \
    (const __attribute__((address_space(1))) void*)(gp), \
    (__attribute__((address_space(3))) void*)(lp), 16, 0, 0)

// ---------- conversions ----------
__global__ __launch_bounds__(256) void cvt_x_kernel(const float* __restrict__ in,
                                                    u16* __restrict__ out, int n4) {
    int i = blockIdx.x * 256 + threadIdx.x;
    if (i >= n4) return;
    float4 v = ((const float4*)in)[i];
    ushort4 o;
    o.x = f2b(v.x); o.y = f2b(v.y); o.z = f2b(v.z); o.w = f2b(v.w);
    ((ushort4*)out)[i] = o;
}

__global__ __launch_bounds__(256) void transpose_bf16_kernel(const float* __restrict__ in,
                                                             u16* __restrict__ out, int R, int C) {
    int idx = blockIdx.x * 256 + threadIdx.x;
    if (idx >= R * C) return;
    int r = idx / C, c = idx - r * C;
    out[(size_t)c * R + r] = f2b(in[idx]);
}

// ---------- pass 1: coarse scatter into (node>>7, blockIdx&7) sub-buckets ----------
// blockIdx&7 approximates the XCD (round-robin dispatch) -> each sub-bucket's
// cursor + data lines are touched by ONE XCD -> L2-local atomics + write combining.
__global__ __launch_bounds__(256) void coarse_scatter_kernel(const int* __restrict__ src,
                                                             const int* __restrict__ dst,
                                                             int* __restrict__ cur,
                                                             uint2* __restrict__ ebuf) {
    int e4 = blockIdx.x * 256 + threadIdx.x;
    int xp = blockIdx.x & 7;
    int4 d = ((const int4*)dst)[e4];
    int4 s = ((const int4*)src)[e4];
    int sub0 = (d.x >> 7) * 8 + xp;
    int sub1 = (d.y >> 7) * 8 + xp;
    int sub2 = (d.z >> 7) * 8 + xp;
    int sub3 = (d.w >> 7) * 8 + xp;
    int p0 = atomicAdd(&cur[sub0 * 16], 1);   // cursors padded to 64B
    int p1 = atomicAdd(&cur[sub1 * 16], 1);
    int p2 = atomicAdd(&cur[sub2 * 16], 1);
    int p3 = atomicAdd(&cur[sub3 * 16], 1);
    if (p0 < SUBCAP) ebuf[(size_t)sub0 * SUBCAP + p0] = make_uint2((unsigned)s.x, (unsigned)d.x);
    if (p1 < SUBCAP) ebuf[(size_t)sub1 * SUBCAP + p1] = make_uint2((unsigned)s.y, (unsigned)d.y);
    if (p2 < SUBCAP) ebuf[(size_t)sub2 * SUBCAP + p2] = make_uint2((unsigned)s.z, (unsigned)d.z);
    if (p3 < SUBCAP) ebuf[(size_t)sub3 * SUBCAP + p3] = make_uint2((unsigned)s.w, (unsigned)d.w);
}

// ---------- pass 2: fine bucketing, one block per coarse bucket ----------
// Block cb owns nodes [cb*128, cb*128+128): cnt region = 512B, esrc region = 64KB,
// both 64B-aligned and touched by exactly one block -> L2-local, combines fully.
__global__ __launch_bounds__(256) void fine_bucket_kernel(const uint2* __restrict__ ebuf,
                                                          const int* __restrict__ cur,
                                                          int* __restrict__ cnt,
                                                          int* __restrict__ esrc) {
    int cb = blockIdx.x;
#pragma unroll 1
    for (int xp = 0; xp < 8; ++xp) {
        int sub = cb * 8 + xp;
        int n = cur[sub * 16];
        if (n > SUBCAP) n = SUBCAP;
        const uint2* base = ebuf + (size_t)sub * SUBCAP;
        for (int i = threadIdx.x; i < n; i += 256) {
            uint2 e = base[i];
            int dd = (int)e.y, ss = (int)e.x;
            int pos = atomicAdd(&cnt[dd], 1);
            if (pos < BUCKET) esrc[(size_t)dd * BUCKET + pos] = ss;
        }
    }
}

// ---------- per-node attention: 1 wave per node; lane = (head, edge_slot) ----------
// h = lane>>3 (8 heads), slot = lane&7 (8 edge slots per iteration).
// Each lane computes the FULL 32-dim dot for its (edge, head).
// KV8: [node][512] bytes fp8 e4m3 — K in bytes 0..255 (dim=byte), V in 256..511.
// Private online softmax per lane (defer-max thr=4); one butterfly merge per node.
// Q and msg may alias (Q[node] fully read into regs before msg[node] written).
__global__ __launch_bounds__(256) void attn_kernel(
    const u16* Q, const u8* __restrict__ KV8,
    const int* __restrict__ cnt, const int* __restrict__ esrc,
    u16* msg) {
    int node = blockIdx.x * 4 + (threadIdx.x >> 6);
    int lane = threadIdx.x & 63;
    int h = lane >> 3;
    int slot = lane & 7;
    int r0 = node * BUCKET;
    int r1 = r0 + min(cnt[node], BUCKET);

    float q[32];
    {
        const uint4* qp = (const uint4*)(Q + (size_t)node * 256 + h * 32);
#pragma unroll
        for (int i = 0; i < 4; ++i) {
            uint4 wv = qp[i];
            q[i * 8 + 0] = B2LO(wv.x) * COEF; q[i * 8 + 1] = B2HI(wv.x) * COEF;
            q[i * 8 + 2] = B2LO(wv.y) * COEF; q[i * 8 + 3] = B2HI(wv.y) * COEF;
            q[i * 8 + 4] = B2LO(wv.z) * COEF; q[i * 8 + 5] = B2HI(wv.z) * COEF;
            q[i * 8 + 6] = B2LO(wv.w) * COEF; q[i * 8 + 7] = B2HI(wv.w) * COEF;
        }
    }

    float m = -3.0e38f, denom = 0.0f;
    float acc[32];
#pragma unroll
    for (int i = 0; i < 32; ++i) acc[i] = 0.0f;

// 4 fp8 values in dword u -> dot with q[i0..i0+3]
#define DOT4F8(u, i0) { f32x2 lo = __builtin_amdgcn_cvt_pk_f32_fp8(u, false); \
                        f32x2 hi = __builtin_amdgcn_cvt_pk_f32_fp8(u, true);  \
                        d += q[i0] * lo[0] + q[(i0)+1] * lo[1];               \
                        d += q[(i0)+2] * hi[0] + q[(i0)+3] * hi[1]; }
#define ACC4(u, i0) { f32x2 lo = __builtin_amdgcn_cvt_pk_f32_fp8(u, false); \
                      f32x2 hi = __builtin_amdgcn_cvt_pk_f32_fp8(u, true);  \
                      acc[i0]     = __builtin_fmaf(ex, lo[0], acc[i0]);     \
                      acc[(i0)+1] = __builtin_fmaf(ex, lo[1], acc[(i0)+1]); \
                      acc[(i0)+2] = __builtin_fmaf(ex, hi[0], acc[(i0)+2]); \
                      acc[(i0)+3] = __builtin_fmaf(ex, hi[1], acc[(i0)+3]); }

    for (int base = r0; base < r1; base += 8) {
        int myj = base + slot;
        bool valid = myj < r1;
        int s = valid ? esrc[myj] : 0;      // exec-masked load; s=0 rows cached+unused
        const uint4* kp = (const uint4*)(KV8 + (size_t)s * 512 + h * 32);
        uint4 ka = kp[0], kb = kp[1];       // 32 fp8 K values
        uint4 va = kp[16], vb = kp[17];     // +256B: 32 fp8 V values

        float d = 0.0f;
        DOT4F8(ka.x, 0);  DOT4F8(ka.y, 4);  DOT4F8(ka.z, 8);  DOT4F8(ka.w, 12);
        DOT4F8(kb.x, 16); DOT4F8(kb.y, 20); DOT4F8(kb.z, 24); DOT4F8(kb.w, 28);
        if (!valid) d = -3.0e38f;

        if (d > m + 4.0f) {                 // defer-max: rescale only on big growth
            float scale = __expf(m - d);
            m = d;
            denom *= scale;
#pragma unroll
            for (int i = 0; i < 32; ++i) acc[i] *= scale;
        }
        float ex = valid ? __expf(d - m) : 0.0f;   // bounded by e^4
        denom += ex;
        ACC4(va.x, 0);  ACC4(va.y, 4);  ACC4(va.z, 8);  ACC4(va.w, 12);
        ACC4(vb.x, 16); ACC4(vb.y, 20); ACC4(vb.z, 24); ACC4(vb.w, 28);
    }

    // ---- per-node merge across the 8 slots ----
    float mg = fmaxf(m, __shfl_xor(m, 1));
    mg = fmaxf(mg, __shfl_xor(mg, 2));
    mg = fmaxf(mg, __shfl_xor(mg, 4));
    float f = __expf(m - mg);
    float dn = denom * f;
    dn += __shfl_xor(dn, 1);
    dn += __shfl_xor(dn, 2);
    dn += __shfl_xor(dn, 4);
#pragma unroll
    for (int i = 0; i < 32; ++i) acc[i] *= f;

    float t16[16];
#pragma unroll
    for (int i = 0; i < 16; ++i) {
        float send = (slot & 1) ? acc[i] : acc[i + 16];
        float recv = __shfl_xor(send, 1);
        t16[i] = ((slot & 1) ? acc[i + 16] : acc[i]) + recv;
    }
    float t8[8];
#pragma unroll
    for (int i = 0; i < 8; ++i) {
        float send = (slot & 2) ? t16[i] : t16[i + 8];
        float recv = __shfl_xor(send, 2);
        t8[i] = ((slot & 2) ? t16[i + 8] : t16[i]) + recv;
    }
    float t4[4];
#pragma unroll
    for (int i = 0; i < 4; ++i) {
        float send = (slot & 4) ? t8[i] : t8[i + 4];
        float recv = __shfl_xor(send, 4);
        t4[i] = ((slot & 4) ? t8[i + 4] : t8[i]) + recv;
    }
    int dimbase = ((slot & 1) << 4) | ((slot & 2) << 2) | (slot & 4);

    float inv = 1.0f / fmaxf(dn, 1e-20f);
    ushort4 o;
    o.x = f2b(t4[0] * inv); o.y = f2b(t4[1] * inv);
    o.z = f2b(t4[2] * inv); o.w = f2b(t4[3] * inv);
    *(ushort4*)(msg + (size_t)node * 256 + h * 32 + dimbase) = o;
}

// ---------- bf16 MFMA GEMM, BK=64, XOR-swizzled LDS ----------
// C(M x Ntot) = A(M x Ktot) * Bt(Ntot x Ktot)^T + bias
// MODE 0: fp32 out. MODE 1: Q bf16 + fused KV8 fp8 rows.
// A row stride fixed 256; k<splitK reads A else A2 (virtual concat).
template <int MODE>
__global__ __launch_bounds__(256) void gemm_bt_kernel(
    const u16* __restrict__ A, const u16* __restrict__ A2, int splitK,
    const u16* __restrict__ Bt, const float* __restrict__ bias,
    int M, int Ntot, int Ktot, int ntiles_n,
    float* __restrict__ outF, u16* __restrict__ outQ, u8* __restrict__ outKV) {
    __shared__ u16 As[128 * 64];
    __shared__ u16 Bs[128 * 64];
    const int tid = threadIdx.x;
    const int lane = tid & 63, wave = tid >> 6;
    const int wm = wave >> 1, wn = wave & 1;
    const int bm = blockIdx.x / ntiles_n, bn = blockIdx.x % ntiles_n;
    const int brow = bm * 128, bcol = bn * 128;

    f32x4 acc[4][4] = {};

    for (int k0 = 0; k0 < Ktot; k0 += 64) {
        const u16* Ab = (k0 < splitK) ? (A + k0) : (A2 + (k0 - splitK));
#pragma unroll
        for (int it = 0; it < 4; ++it) {
            int chunk = it * 256 + tid;          // 0..1023
            int row = chunk >> 3;                // 0..127
            int cg = chunk & 7;                  // 16B column-group
            int gcg = cg ^ (row & 7);            // inverse-swizzled global source
            int ga = brow + row; if (ga > M - 1) ga = M - 1;
            GLDS16(Ab + (size_t)ga * 256 + gcg * 8, As + (it * 256 + wave * 64) * 8);
            GLDS16(Bt + (size_t)(bcol + row) * Ktot + k0 + gcg * 8,
                   Bs + (it * 256 + wave * 64) * 8);
        }
        __syncthreads();
        const int kg = lane >> 4, rI = lane & 15, rx = lane & 7;
#pragma unroll
        for (int ks = 0; ks < 2; ++ks) {
            bf16x8 a[4], b[4];
#pragma unroll
            for (int m = 0; m < 4; ++m)
                a[m] = *(const bf16x8*)(As + (wm * 64 + m * 16 + rI) * 64 +
                                        (((ks * 4 + kg) ^ rx) * 8));
#pragma unroll
            for (int n = 0; n < 4; ++n)
                b[n] = *(const bf16x8*)(Bs + (wn * 64 + n * 16 + rI) * 64 +
                                        (((ks * 4 + kg) ^ rx) * 8));
#pragma unroll
            for (int m = 0; m < 4; ++m)
#pragma unroll
                for (int n = 0; n < 4; ++n)
                    acc[m][n] = __builtin_amdgcn_mfma_f32_16x16x32_bf16(a[m], b[n], acc[m][n], 0, 0, 0);
        }
        __syncthreads();
    }

#pragma unroll
    for (int m = 0; m < 4; ++m) {
        int growb = brow + wm * 64 + m * 16 + (lane >> 4) * 4;
#pragma unroll
        for (int n = 0; n < 4; ++n) {
            int gcol = bcol + wn * 64 + n * 16 + (lane & 15);
            float bi = bias[gcol];
#pragma unroll
            for (int r = 0; r < 4; ++r) {
                int grow = growb + r;
                if (grow >= M) continue;
                float c = acc[m][n][r] + bi;
                if (MODE == 0) {
                    outF[(size_t)grow * Ntot + gcol] = c;
                } else {
                    int hh = gcol / 96;
                    int rr = gcol - hh * 96;
                    int sel = rr >> 5;
                    int cc = hh * 32 + (rr & 31);
                    if (sel == 0) {
                        outQ[(size_t)grow * 256 + cc] = f2b(c);
                    } else {
                        unsigned pv = __builtin_amdgcn_cvt_pk_fp8_f32(c, c, 0, false);
                        outKV[(size_t)grow * 512 + (sel - 1) * 256 + cc] = (u8)(pv & 0xff);
                    }
                }
            }
        }
    }
}

extern "C" void kernel_launch(void* const* d_in, const int* in_sizes, int n_in,
                              void* d_out, int out_size, void* d_ws, size_t ws_size,
                              hipStream_t stream) {
    const float* x = (const float*)d_in[0];
    const float* W_qkv = (const float*)d_in[1];
    const float* b_qkv = (const float*)d_in[2];
    const float* W_out = (const float*)d_in[3];
    const float* b_out = (const float*)d_in[4];
    const int* src = (const int*)d_in[5];
    const int* dst = (const int*)d_in[6];
    float* out = (float*)d_out;

    char* w = (char*)d_ws;
    size_t off = 0;
    auto alloc = [&](size_t bytes) -> char* {
        char* p = w + off;
        off += (bytes + 255) & ~(size_t)255;
        return p;
    };
    u16* xb = (u16*)alloc((size_t)NN * 256 * 2);
    u16* WbT = (u16*)alloc((size_t)768 * 256 * 2);
    u16* WoT = (u16*)alloc((size_t)256 * 512 * 2);
    u16* Qb = (u16*)alloc((size_t)NN * 256 * 2);
    u8* KV8 = (u8*)alloc((size_t)NN * 512);
    u16* msg = Qb;  // alias: attn reads Q[node] fully into regs before writing msg[node]
    int* cnt = (int*)alloc((size_t)NN * 4);
    int* esrc = (int*)alloc((size_t)NN * BUCKET * 4);
    int* cur = (int*)alloc((size_t)NB * 8 * 16 * 4);                 // padded cursors, 400 KB
    uint2* ebuf = (uint2*)alloc((size_t)NB * 8 * SUBCAP * 8);        // 38.4 MB
    // total workspace ~ 245 MB

    hipMemsetAsync(cnt, 0, (size_t)NN * 4, stream);
    hipMemsetAsync(cur, 0, (size_t)NB * 8 * 16 * 4, stream);

    cvt_x_kernel<<<25000, 256, 0, stream>>>(x, xb, NN * 256 / 4);
    transpose_bf16_kernel<<<(256 * 768 + 255) / 256, 256, 0, stream>>>(W_qkv, WbT, 256, 768);
    transpose_bf16_kernel<<<(512 * 256 + 255) / 256, 256, 0, stream>>>(W_out, WoT, 512, 256);

    coarse_scatter_kernel<<<EE / 1024, 256, 0, stream>>>(src, dst, cur, ebuf);
    fine_bucket_kernel<<<NB, 256, 0, stream>>>(ebuf, cur, cnt, esrc);

    // QKV = xb @ W_qkv + b_qkv  -> Q bf16 + fused KV8 fp8
    gemm_bt_kernel<1><<<782 * 6, 256, 0, stream>>>(xb, xb, 256, WbT, b_qkv, NN, 768, 256, 6,
                                                   nullptr, Qb, KV8);

    attn_kernel<<<NN / 4, 256, 0, stream>>>(Qb, KV8, cnt, esrc, msg);

    // out = [xb | msg] @ W_out + b_out  (fp32 out)
    gemm_bt_kernel<0><<<782 * 2, 256, 0, stream>>>(xb, msg, 256, WoT, b_out, NN, 256, 512, 2,
                                                   out, nullptr, nullptr);
}

// Round 9
// 669.036 us; speedup vs baseline: 1.1382x; 1.0037x over previous
//
#include <hip/hip_runtime.h>
#include <hip/hip_bf16.h>

typedef unsigned short u16;
typedef unsigned char u8;
typedef short bf16x8 __attribute__((ext_vector_type(8)));
typedef float f32x4 __attribute__((ext_vector_type(4)));
typedef float f32x2 __attribute__((ext_vector_type(2)));

#define NN 100000
#define EE 3200000
#define BUCKET 128
#define NB 782          // coarse buckets: node>>7, 128 nodes each
#define SUBCAP 768      // capacity per (coarse, xcd) sub-bucket
static constexpr float COEF = 0.17677669529663687f; // 1/sqrt(32)

__device__ __forceinline__ u16 f2b(float f) {
    unsigned u = __float_as_uint(f);
    unsigned r = (u + 0x7fffu + ((u >> 16) & 1u)) >> 16;
    return (u16)r;
}

#define B2LO(w) __uint_as_float((w) << 16)
#define B2HI(w) __uint_as_float((w) & 0xffff0000u)

#define GLDS16(gp, lp) __builtin_amdgcn_global_load_lds( \
    (const __attribute__((address_space(1))) void*)(gp), \
    (__attribute__((address_space(3))) void*)(lp), 16, 0, 0)

// ---------- conversions ----------
__global__ __launch_bounds__(256) void cvt_x_kernel(const float* __restrict__ in,
                                                    u16* __restrict__ out, int n4) {
    int i = blockIdx.x * 256 + threadIdx.x;
    if (i >= n4) return;
    float4 v = ((const float4*)in)[i];
    ushort4 o;
    o.x = f2b(v.x); o.y = f2b(v.y); o.z = f2b(v.z); o.w = f2b(v.w);
    ((ushort4*)out)[i] = o;
}

__global__ __launch_bounds__(256) void transpose_bf16_kernel(const float* __restrict__ in,
                                                             u16* __restrict__ out, int R, int C) {
    int idx = blockIdx.x * 256 + threadIdx.x;
    if (idx >= R * C) return;
    int r = idx / C, c = idx - r * C;
    out[(size_t)c * R + r] = f2b(in[idx]);
}

// ---------- pass 1: coarse scatter into (node>>7, blockIdx&7) sub-buckets ----------
__global__ __launch_bounds__(256) void coarse_scatter_kernel(const int* __restrict__ src,
                                                             const int* __restrict__ dst,
                                                             int* __restrict__ cur,
                                                             uint2* __restrict__ ebuf) {
    int e4 = blockIdx.x * 256 + threadIdx.x;
    int xp = blockIdx.x & 7;
    int4 d = ((const int4*)dst)[e4];
    int4 s = ((const int4*)src)[e4];
    int sub0 = (d.x >> 7) * 8 + xp;
    int sub1 = (d.y >> 7) * 8 + xp;
    int sub2 = (d.z >> 7) * 8 + xp;
    int sub3 = (d.w >> 7) * 8 + xp;
    int p0 = atomicAdd(&cur[sub0 * 16], 1);   // cursors padded to 64B
    int p1 = atomicAdd(&cur[sub1 * 16], 1);
    int p2 = atomicAdd(&cur[sub2 * 16], 1);
    int p3 = atomicAdd(&cur[sub3 * 16], 1);
    if (p0 < SUBCAP) ebuf[(size_t)sub0 * SUBCAP + p0] = make_uint2((unsigned)s.x, (unsigned)d.x);
    if (p1 < SUBCAP) ebuf[(size_t)sub1 * SUBCAP + p1] = make_uint2((unsigned)s.y, (unsigned)d.y);
    if (p2 < SUBCAP) ebuf[(size_t)sub2 * SUBCAP + p2] = make_uint2((unsigned)s.z, (unsigned)d.z);
    if (p3 < SUBCAP) ebuf[(size_t)sub3 * SUBCAP + p3] = make_uint2((unsigned)s.w, (unsigned)d.w);
}

// ---------- pass 2: fine bucketing, one block per coarse bucket ----------
__global__ __launch_bounds__(256) void fine_bucket_kernel(const uint2* __restrict__ ebuf,
                                                          const int* __restrict__ cur,
                                                          int* __restrict__ cnt,
                                                          int* __restrict__ esrc) {
    int cb = blockIdx.x;
#pragma unroll 1
    for (int xp = 0; xp < 8; ++xp) {
        int sub = cb * 8 + xp;
        int n = cur[sub * 16];
        if (n > SUBCAP) n = SUBCAP;
        const uint2* base = ebuf + (size_t)sub * SUBCAP;
        for (int i = threadIdx.x; i < n; i += 256) {
            uint2 e = base[i];
            int dd = (int)e.y, ss = (int)e.x;
            int pos = atomicAdd(&cnt[dd], 1);
            if (pos < BUCKET) esrc[(size_t)dd * BUCKET + pos] = ss;
        }
    }
}

// ---------- per-node attention: 1 wave per node; lane = (head, edge_slot) ----------
// h = lane>>3 (8 heads), slot = lane&7. Each lane processes 2 edges per iter
// (16 edges/wave-iter) -> 8 dwordx4 gathers in flight. Full 32-dim dot per lane.
// KV8: [node][512] bytes fp8 e4m3 — K bytes 0..255, V bytes 256..511.
// Packed f32x2 math (v_pk_fma via -ffp-contract). Defer-max (thr=4) online softmax.
// Q and msg may alias (Q[node] fully read into regs before msg[node] written).
__global__ __launch_bounds__(256) void attn_kernel(
    const u16* Q, const u8* __restrict__ KV8,
    const int* __restrict__ cnt, const int* __restrict__ esrc,
    u16* msg) {
    int node = blockIdx.x * 4 + (threadIdx.x >> 6);
    int lane = threadIdx.x & 63;
    int h = lane >> 3;
    int slot = lane & 7;
    int r0 = node * BUCKET;
    int r1 = r0 + min(cnt[node], BUCKET);

    // q for head h (pre-scaled by COEF), packed as 16 x f32x2
    f32x2 q2[16];
    {
        const uint4* qp = (const uint4*)(Q + (size_t)node * 256 + h * 32);
#pragma unroll
        for (int i = 0; i < 4; ++i) {
            uint4 wv = qp[i];
            q2[i * 4 + 0] = f32x2{B2LO(wv.x) * COEF, B2HI(wv.x) * COEF};
            q2[i * 4 + 1] = f32x2{B2LO(wv.y) * COEF, B2HI(wv.y) * COEF};
            q2[i * 4 + 2] = f32x2{B2LO(wv.z) * COEF, B2HI(wv.z) * COEF};
            q2[i * 4 + 3] = f32x2{B2LO(wv.w) * COEF, B2HI(wv.w) * COEF};
        }
    }

    float m = -3.0e38f, denom = 0.0f;
    f32x2 acc2[16];
#pragma unroll
    for (int i = 0; i < 16; ++i) acc2[i] = f32x2{0.0f, 0.0f};

// dword u holds 4 fp8 = dims for q2[j0], q2[j0+1]
#define DOTP(dd, u, j0) { f32x2 lo = __builtin_amdgcn_cvt_pk_f32_fp8(u, false); \
                          f32x2 hi = __builtin_amdgcn_cvt_pk_f32_fp8(u, true);  \
                          dd += q2[j0] * lo; dd += q2[(j0) + 1] * hi; }
#define ACCP(e2, u, j0) { f32x2 lo = __builtin_amdgcn_cvt_pk_f32_fp8(u, false); \
                          f32x2 hi = __builtin_amdgcn_cvt_pk_f32_fp8(u, true);  \
                          acc2[j0] += e2 * lo; acc2[(j0) + 1] += e2 * hi; }

    for (int base = r0; base < r1; base += 16) {
        int ja = base + slot, jb = base + 8 + slot;
        bool vA = ja < r1, vB = jb < r1;
        int sA = vA ? esrc[ja] : 0;
        int sB = vB ? esrc[jb] : 0;
        const uint4* pA = (const uint4*)(KV8 + (size_t)sA * 512 + h * 32);
        const uint4* pB = (const uint4*)(KV8 + (size_t)sB * 512 + h * 32);
        // 8 independent dwordx4 gathers in flight
        uint4 kA0 = pA[0], kA1 = pA[1], vA0 = pA[16], vA1 = pA[17];
        uint4 kB0 = pB[0], kB1 = pB[1], vB0 = pB[16], vB1 = pB[17];

        f32x2 dA2 = {0.0f, 0.0f}, dB2 = {0.0f, 0.0f};
        DOTP(dA2, kA0.x, 0);  DOTP(dA2, kA0.y, 2);  DOTP(dA2, kA0.z, 4);  DOTP(dA2, kA0.w, 6);
        DOTP(dA2, kA1.x, 8);  DOTP(dA2, kA1.y, 10); DOTP(dA2, kA1.z, 12); DOTP(dA2, kA1.w, 14);
        DOTP(dB2, kB0.x, 0);  DOTP(dB2, kB0.y, 2);  DOTP(dB2, kB0.z, 4);  DOTP(dB2, kB0.w, 6);
        DOTP(dB2, kB1.x, 8);  DOTP(dB2, kB1.y, 10); DOTP(dB2, kB1.z, 12); DOTP(dB2, kB1.w, 14);
        float dA = vA ? (dA2[0] + dA2[1]) : -3.0e38f;
        float dB = vB ? (dB2[0] + dB2[1]) : -3.0e38f;

        float dm = fmaxf(dA, dB);
        if (dm > m + 4.0f) {                // defer-max: rescale only on big growth
            float scale = __expf(m - dm);
            m = dm;
            denom *= scale;
            f32x2 s2 = {scale, scale};
#pragma unroll
            for (int i = 0; i < 16; ++i) acc2[i] *= s2;
        }
        float exA = vA ? __expf(dA - m) : 0.0f;   // bounded by e^4
        float exB = vB ? __expf(dB - m) : 0.0f;
        denom += exA + exB;
        f32x2 eA2 = {exA, exA}, eB2 = {exB, exB};
        ACCP(eA2, vA0.x, 0);  ACCP(eA2, vA0.y, 2);  ACCP(eA2, vA0.z, 4);  ACCP(eA2, vA0.w, 6);
        ACCP(eA2, vA1.x, 8);  ACCP(eA2, vA1.y, 10); ACCP(eA2, vA1.z, 12); ACCP(eA2, vA1.w, 14);
        ACCP(eB2, vB0.x, 0);  ACCP(eB2, vB0.y, 2);  ACCP(eB2, vB0.z, 4);  ACCP(eB2, vB0.w, 6);
        ACCP(eB2, vB1.x, 8);  ACCP(eB2, vB1.y, 10); ACCP(eB2, vB1.z, 12); ACCP(eB2, vB1.w, 14);
    }

    // ---- per-node merge across the 8 slots ----
    float mg = fmaxf(m, __shfl_xor(m, 1));
    mg = fmaxf(mg, __shfl_xor(mg, 2));
    mg = fmaxf(mg, __shfl_xor(mg, 4));
    float f = __expf(m - mg);
    float dn = denom * f;
    dn += __shfl_xor(dn, 1);
    dn += __shfl_xor(dn, 2);
    dn += __shfl_xor(dn, 4);
    float acc[32];
#pragma unroll
    for (int i = 0; i < 16; ++i) {
        acc[2 * i] = acc2[i][0] * f;
        acc[2 * i + 1] = acc2[i][1] * f;
    }

    float t16[16];
#pragma unroll
    for (int i = 0; i < 16; ++i) {
        float send = (slot & 1) ? acc[i] : acc[i + 16];
        float recv = __shfl_xor(send, 1);
        t16[i] = ((slot & 1) ? acc[i + 16] : acc[i]) + recv;
    }
    float t8[8];
#pragma unroll
    for (int i = 0; i < 8; ++i) {
        float send = (slot & 2) ? t16[i] : t16[i + 8];
        float recv = __shfl_xor(send, 2);
        t8[i] = ((slot & 2) ? t16[i + 8] : t16[i]) + recv;
    }
    float t4[4];
#pragma unroll
    for (int i = 0; i < 4; ++i) {
        float send = (slot & 4) ? t8[i] : t8[i + 4];
        float recv = __shfl_xor(send, 4);
        t4[i] = ((slot & 4) ? t8[i + 4] : t8[i]) + recv;
    }
    int dimbase = ((slot & 1) << 4) | ((slot & 2) << 2) | (slot & 4);

    float inv = 1.0f / fmaxf(dn, 1e-20f);
    ushort4 o;
    o.x = f2b(t4[0] * inv); o.y = f2b(t4[1] * inv);
    o.z = f2b(t4[2] * inv); o.w = f2b(t4[3] * inv);
    *(ushort4*)(msg + (size_t)node * 256 + h * 32 + dimbase) = o;
}

// ---------- bf16 MFMA GEMM, BK=64, XOR-swizzled LDS ----------
template <int MODE>
__global__ __launch_bounds__(256) void gemm_bt_kernel(
    const u16* __restrict__ A, const u16* __restrict__ A2, int splitK,
    const u16* __restrict__ Bt, const float* __restrict__ bias,
    int M, int Ntot, int Ktot, int ntiles_n,
    float* __restrict__ outF, u16* __restrict__ outQ, u8* __restrict__ outKV) {
    __shared__ u16 As[128 * 64];
    __shared__ u16 Bs[128 * 64];
    const int tid = threadIdx.x;
    const int lane = tid & 63, wave = tid >> 6;
    const int wm = wave >> 1, wn = wave & 1;
    const int bm = blockIdx.x / ntiles_n, bn = blockIdx.x % ntiles_n;
    const int brow = bm * 128, bcol = bn * 128;

    f32x4 acc[4][4] = {};

    for (int k0 = 0; k0 < Ktot; k0 += 64) {
        const u16* Ab = (k0 < splitK) ? (A + k0) : (A2 + (k0 - splitK));
#pragma unroll
        for (int it = 0; it < 4; ++it) {
            int chunk = it * 256 + tid;          // 0..1023
            int row = chunk >> 3;                // 0..127
            int cg = chunk & 7;                  // 16B column-group
            int gcg = cg ^ (row & 7);            // inverse-swizzled global source
            int ga = brow + row; if (ga > M - 1) ga = M - 1;
            GLDS16(Ab + (size_t)ga * 256 + gcg * 8, As + (it * 256 + wave * 64) * 8);
            GLDS16(Bt + (size_t)(bcol + row) * Ktot + k0 + gcg * 8,
                   Bs + (it * 256 + wave * 64) * 8);
        }
        __syncthreads();
        const int kg = lane >> 4, rI = lane & 15, rx = lane & 7;
#pragma unroll
        for (int ks = 0; ks < 2; ++ks) {
            bf16x8 a[4], b[4];
#pragma unroll
            for (int m = 0; m < 4; ++m)
                a[m] = *(const bf16x8*)(As + (wm * 64 + m * 16 + rI) * 64 +
                                        (((ks * 4 + kg) ^ rx) * 8));
#pragma unroll
            for (int n = 0; n < 4; ++n)
                b[n] = *(const bf16x8*)(Bs + (wn * 64 + n * 16 + rI) * 64 +
                                        (((ks * 4 + kg) ^ rx) * 8));
#pragma unroll
            for (int m = 0; m < 4; ++m)
#pragma unroll
                for (int n = 0; n < 4; ++n)
                    acc[m][n] = __builtin_amdgcn_mfma_f32_16x16x32_bf16(a[m], b[n], acc[m][n], 0, 0, 0);
        }
        __syncthreads();
    }

#pragma unroll
    for (int m = 0; m < 4; ++m) {
        int growb = brow + wm * 64 + m * 16 + (lane >> 4) * 4;
#pragma unroll
        for (int n = 0; n < 4; ++n) {
            int gcol = bcol + wn * 64 + n * 16 + (lane & 15);
            float bi = bias[gcol];
#pragma unroll
            for (int r = 0; r < 4; ++r) {
                int grow = growb + r;
                if (grow >= M) continue;
                float c = acc[m][n][r] + bi;
                if (MODE == 0) {
                    outF[(size_t)grow * Ntot + gcol] = c;
                } else {
                    int hh = gcol / 96;
                    int rr = gcol - hh * 96;
                    int sel = rr >> 5;
                    int cc = hh * 32 + (rr & 31);
                    if (sel == 0) {
                        outQ[(size_t)grow * 256 + cc] = f2b(c);
                    } else {
                        unsigned pv = __builtin_amdgcn_cvt_pk_fp8_f32(c, c, 0, false);
                        outKV[(size_t)grow * 512 + (sel - 1) * 256 + cc] = (u8)(pv & 0xff);
                    }
                }
            }
        }
    }
}

extern "C" void kernel_launch(void* const* d_in, const int* in_sizes, int n_in,
                              void* d_out, int out_size, void* d_ws, size_t ws_size,
                              hipStream_t stream) {
    const float* x = (const float*)d_in[0];
    const float* W_qkv = (const float*)d_in[1];
    const float* b_qkv = (const float*)d_in[2];
    const float* W_out = (const float*)d_in[3];
    const float* b_out = (const float*)d_in[4];
    const int* src = (const int*)d_in[5];
    const int* dst = (const int*)d_in[6];
    float* out = (float*)d_out;

    char* w = (char*)d_ws;
    size_t off = 0;
    auto alloc = [&](size_t bytes) -> char* {
        char* p = w + off;
        off += (bytes + 255) & ~(size_t)255;
        return p;
    };
    u16* xb = (u16*)alloc((size_t)NN * 256 * 2);
    u16* WbT = (u16*)alloc((size_t)768 * 256 * 2);
    u16* WoT = (u16*)alloc((size_t)256 * 512 * 2);
    u16* Qb = (u16*)alloc((size_t)NN * 256 * 2);
    u8* KV8 = (u8*)alloc((size_t)NN * 512);
    u16* msg = Qb;  // alias: attn reads Q[node] fully into regs before writing msg[node]
    int* cnt = (int*)alloc((size_t)NN * 4);
    int* esrc = (int*)alloc((size_t)NN * BUCKET * 4);
    int* cur = (int*)alloc((size_t)NB * 8 * 16 * 4);                 // padded cursors
    uint2* ebuf = (uint2*)alloc((size_t)NB * 8 * SUBCAP * 8);        // 38.4 MB
    // total workspace ~ 245 MB

    hipMemsetAsync(cnt, 0, (size_t)NN * 4, stream);
    hipMemsetAsync(cur, 0, (size_t)NB * 8 * 16 * 4, stream);

    cvt_x_kernel<<<25000, 256, 0, stream>>>(x, xb, NN * 256 / 4);
    transpose_bf16_kernel<<<(256 * 768 + 255) / 256, 256, 0, stream>>>(W_qkv, WbT, 256, 768);
    transpose_bf16_kernel<<<(512 * 256 + 255) / 256, 256, 0, stream>>>(W_out, WoT, 512, 256);

    coarse_scatter_kernel<<<EE / 1024, 256, 0, stream>>>(src, dst, cur, ebuf);
    fine_bucket_kernel<<<NB, 256, 0, stream>>>(ebuf, cur, cnt, esrc);

    // QKV = xb @ W_qkv + b_qkv  -> Q bf16 + fused KV8 fp8
    gemm_bt_kernel<1><<<782 * 6, 256, 0, stream>>>(xb, xb, 256, WbT, b_qkv, NN, 768, 256, 6,
                                                   nullptr, Qb, KV8);

    attn_kernel<<<NN / 4, 256, 0, stream>>>(Qb, KV8, cnt, esrc, msg);

    // out = [xb | msg] @ W_out + b_out  (fp32 out)
    gemm_bt_kernel<0><<<782 * 2, 256, 0, stream>>>(xb, msg, 256, WoT, b_out, NN, 256, 512, 2,
                                                   out, nullptr, nullptr);
}

// Round 10
// 643.972 us; speedup vs baseline: 1.1825x; 1.0389x over previous
//
#include <hip/hip_runtime.h>
#include <hip/hip_bf16.h>

typedef unsigned short u16;
typedef unsigned char u8;
typedef short bf16x8 __attribute__((ext_vector_type(8)));
typedef float f32x4 __attribute__((ext_vector_type(4)));
typedef float f32x2 __attribute__((ext_vector_type(2)));

#define NN 100000
#define EE 3200000
#define BUCKET 128
#define NB 782          // coarse buckets: node>>7, 128 nodes each
#define SUBCAP 768      // capacity per (coarse, xcd) sub-bucket

#define COARSE_BLOCKS 3125   // EE/1024 edges, int4 per thread
#define CVT_BLOCKS 25000     // NN*256/4 float4 per thread
#define TR1_BLOCKS 768       // 256x768
#define TR2_BLOCKS 512       // 512x256
#define PREP_BLOCKS (COARSE_BLOCKS + CVT_BLOCKS + TR1_BLOCKS + TR2_BLOCKS)
#define GEMM1_BLOCKS (782 * 6)

static constexpr float COEF = 0.17677669529663687f; // 1/sqrt(32)

__device__ __forceinline__ u16 f2b(float f) {
    unsigned u = __float_as_uint(f);
    unsigned r = (u + 0x7fffu + ((u >> 16) & 1u)) >> 16;
    return (u16)r;
}

#define B2LO(w) __uint_as_float((w) << 16)
#define B2HI(w) __uint_as_float((w) & 0xffff0000u)

#define GLDS16(gp, lp) __builtin_amdgcn_global_load_lds( \
    (const __attribute__((address_space(1))) void*)(gp), \
    (__attribute__((address_space(3))) void*)(lp), 16, 0, 0)

// ---------- prep: coarse_scatter || cvt_x || transpose(W_qkv) || transpose(W_out) ----------
// All four are independent (read only original inputs). Grid-partitioned fusion:
// coarse blocks first (atomic/latency-bound) overlap with cvt blocks (BW-bound).
__global__ __launch_bounds__(256) void prep_kernel(
    const float* __restrict__ x, u16* __restrict__ xb,
    const float* __restrict__ Wq, u16* __restrict__ WbT,
    const float* __restrict__ Wo, u16* __restrict__ WoT,
    const int* __restrict__ src, const int* __restrict__ dst,
    int* __restrict__ cur, uint2* __restrict__ ebuf) {
    int b = blockIdx.x;
    int tid = threadIdx.x;
    if (b < COARSE_BLOCKS) {
        // coarse scatter into (node>>7, blockIdx&7) sub-buckets.
        // blockIdx&7 ~ XCD (round-robin dispatch over the merged grid, coarse occupies
        // blockIdx [0,3125) so b&7 keeps the original XCD affinity).
        int e4 = b * 256 + tid;
        int xp = b & 7;
        int4 d = ((const int4*)dst)[e4];
        int4 s = ((const int4*)src)[e4];
        int sub0 = (d.x >> 7) * 8 + xp;
        int sub1 = (d.y >> 7) * 8 + xp;
        int sub2 = (d.z >> 7) * 8 + xp;
        int sub3 = (d.w >> 7) * 8 + xp;
        int p0 = atomicAdd(&cur[sub0 * 16], 1);   // cursors padded to 64B
        int p1 = atomicAdd(&cur[sub1 * 16], 1);
        int p2 = atomicAdd(&cur[sub2 * 16], 1);
        int p3 = atomicAdd(&cur[sub3 * 16], 1);
        if (p0 < SUBCAP) ebuf[(size_t)sub0 * SUBCAP + p0] = make_uint2((unsigned)s.x, (unsigned)d.x);
        if (p1 < SUBCAP) ebuf[(size_t)sub1 * SUBCAP + p1] = make_uint2((unsigned)s.y, (unsigned)d.y);
        if (p2 < SUBCAP) ebuf[(size_t)sub2 * SUBCAP + p2] = make_uint2((unsigned)s.z, (unsigned)d.z);
        if (p3 < SUBCAP) ebuf[(size_t)sub3 * SUBCAP + p3] = make_uint2((unsigned)s.w, (unsigned)d.w);
        return;
    }
    b -= COARSE_BLOCKS;
    if (b < CVT_BLOCKS) {
        int i = b * 256 + tid;
        float4 v = ((const float4*)x)[i];
        ushort4 o;
        o.x = f2b(v.x); o.y = f2b(v.y); o.z = f2b(v.z); o.w = f2b(v.w);
        ((ushort4*)xb)[i] = o;
        return;
    }
    b -= CVT_BLOCKS;
    if (b < TR1_BLOCKS) {
        int idx = b * 256 + tid;         // W_qkv: 256 x 768
        int r = idx / 768, c = idx - r * 768;
        WbT[(size_t)c * 256 + r] = f2b(Wq[idx]);
        return;
    }
    b -= TR1_BLOCKS;
    {
        int idx = b * 256 + tid;         // W_out: 512 x 256
        int r = idx >> 8, c = idx & 255;
        WoT[(size_t)c * 512 + r] = f2b(Wo[idx]);
    }
}

// ---------- per-node attention: 1 wave per node; lane = (head, edge_slot) ----------
// h = lane>>3 (8 heads), slot = lane&7. Each lane processes 2 edges per iter.
// KV8: [node][512] bytes fp8 e4m3 — K bytes 0..255, V bytes 256..511.
// Packed f32x2 math; defer-max (thr=4) online softmax; butterfly merge per node.
// Q and msg may alias (Q[node] fully read into regs before msg[node] written).
__global__ __launch_bounds__(256) void attn_kernel(
    const u16* Q, const u8* __restrict__ KV8,
    const int* __restrict__ cnt, const int* __restrict__ esrc,
    u16* msg) {
    int node = blockIdx.x * 4 + (threadIdx.x >> 6);
    int lane = threadIdx.x & 63;
    int h = lane >> 3;
    int slot = lane & 7;
    int r0 = node * BUCKET;
    int r1 = r0 + min(cnt[node], BUCKET);

    f32x2 q2[16];
    {
        const uint4* qp = (const uint4*)(Q + (size_t)node * 256 + h * 32);
#pragma unroll
        for (int i = 0; i < 4; ++i) {
            uint4 wv = qp[i];
            q2[i * 4 + 0] = f32x2{B2LO(wv.x) * COEF, B2HI(wv.x) * COEF};
            q2[i * 4 + 1] = f32x2{B2LO(wv.y) * COEF, B2HI(wv.y) * COEF};
            q2[i * 4 + 2] = f32x2{B2LO(wv.z) * COEF, B2HI(wv.z) * COEF};
            q2[i * 4 + 3] = f32x2{B2LO(wv.w) * COEF, B2HI(wv.w) * COEF};
        }
    }

    float m = -3.0e38f, denom = 0.0f;
    f32x2 acc2[16];
#pragma unroll
    for (int i = 0; i < 16; ++i) acc2[i] = f32x2{0.0f, 0.0f};

#define DOTP(dd, u, j0) { f32x2 lo = __builtin_amdgcn_cvt_pk_f32_fp8(u, false); \
                          f32x2 hi = __builtin_amdgcn_cvt_pk_f32_fp8(u, true);  \
                          dd += q2[j0] * lo; dd += q2[(j0) + 1] * hi; }
#define ACCP(e2, u, j0) { f32x2 lo = __builtin_amdgcn_cvt_pk_f32_fp8(u, false); \
                          f32x2 hi = __builtin_amdgcn_cvt_pk_f32_fp8(u, true);  \
                          acc2[j0] += e2 * lo; acc2[(j0) + 1] += e2 * hi; }

    for (int base = r0; base < r1; base += 16) {
        int ja = base + slot, jb = base + 8 + slot;
        bool vA = ja < r1, vB = jb < r1;
        int sA = vA ? esrc[ja] : 0;
        int sB = vB ? esrc[jb] : 0;
        const uint4* pA = (const uint4*)(KV8 + (size_t)sA * 512 + h * 32);
        const uint4* pB = (const uint4*)(KV8 + (size_t)sB * 512 + h * 32);
        uint4 kA0 = pA[0], kA1 = pA[1], vA0 = pA[16], vA1 = pA[17];
        uint4 kB0 = pB[0], kB1 = pB[1], vB0 = pB[16], vB1 = pB[17];

        f32x2 dA2 = {0.0f, 0.0f}, dB2 = {0.0f, 0.0f};
        DOTP(dA2, kA0.x, 0);  DOTP(dA2, kA0.y, 2);  DOTP(dA2, kA0.z, 4);  DOTP(dA2, kA0.w, 6);
        DOTP(dA2, kA1.x, 8);  DOTP(dA2, kA1.y, 10); DOTP(dA2, kA1.z, 12); DOTP(dA2, kA1.w, 14);
        DOTP(dB2, kB0.x, 0);  DOTP(dB2, kB0.y, 2);  DOTP(dB2, kB0.z, 4);  DOTP(dB2, kB0.w, 6);
        DOTP(dB2, kB1.x, 8);  DOTP(dB2, kB1.y, 10); DOTP(dB2, kB1.z, 12); DOTP(dB2, kB1.w, 14);
        float dA = vA ? (dA2[0] + dA2[1]) : -3.0e38f;
        float dB = vB ? (dB2[0] + dB2[1]) : -3.0e38f;

        float dm = fmaxf(dA, dB);
        if (dm > m + 4.0f) {                // defer-max: rescale only on big growth
            float scale = __expf(m - dm);
            m = dm;
            denom *= scale;
            f32x2 s2 = {scale, scale};
#pragma unroll
            for (int i = 0; i < 16; ++i) acc2[i] *= s2;
        }
        float exA = vA ? __expf(dA - m) : 0.0f;   // bounded by e^4
        float exB = vB ? __expf(dB - m) : 0.0f;
        denom += exA + exB;
        f32x2 eA2 = {exA, exA}, eB2 = {exB, exB};
        ACCP(eA2, vA0.x, 0);  ACCP(eA2, vA0.y, 2);  ACCP(eA2, vA0.z, 4);  ACCP(eA2, vA0.w, 6);
        ACCP(eA2, vA1.x, 8);  ACCP(eA2, vA1.y, 10); ACCP(eA2, vA1.z, 12); ACCP(eA2, vA1.w, 14);
        ACCP(eB2, vB0.x, 0);  ACCP(eB2, vB0.y, 2);  ACCP(eB2, vB0.z, 4);  ACCP(eB2, vB0.w, 6);
        ACCP(eB2, vB1.x, 8);  ACCP(eB2, vB1.y, 10); ACCP(eB2, vB1.z, 12); ACCP(eB2, vB1.w, 14);
    }

    // ---- per-node merge across the 8 slots ----
    float mg = fmaxf(m, __shfl_xor(m, 1));
    mg = fmaxf(mg, __shfl_xor(mg, 2));
    mg = fmaxf(mg, __shfl_xor(mg, 4));
    float f = __expf(m - mg);
    float dn = denom * f;
    dn += __shfl_xor(dn, 1);
    dn += __shfl_xor(dn, 2);
    dn += __shfl_xor(dn, 4);
    float acc[32];
#pragma unroll
    for (int i = 0; i < 16; ++i) {
        acc[2 * i] = acc2[i][0] * f;
        acc[2 * i + 1] = acc2[i][1] * f;
    }

    float t16[16];
#pragma unroll
    for (int i = 0; i < 16; ++i) {
        float send = (slot & 1) ? acc[i] : acc[i + 16];
        float recv = __shfl_xor(send, 1);
        t16[i] = ((slot & 1) ? acc[i + 16] : acc[i]) + recv;
    }
    float t8[8];
#pragma unroll
    for (int i = 0; i < 8; ++i) {
        float send = (slot & 2) ? t16[i] : t16[i + 8];
        float recv = __shfl_xor(send, 2);
        t8[i] = ((slot & 2) ? t16[i + 8] : t16[i]) + recv;
    }
    float t4[4];
#pragma unroll
    for (int i = 0; i < 4; ++i) {
        float send = (slot & 4) ? t8[i] : t8[i + 4];
        float recv = __shfl_xor(send, 4);
        t4[i] = ((slot & 4) ? t8[i + 4] : t8[i]) + recv;
    }
    int dimbase = ((slot & 1) << 4) | ((slot & 2) << 2) | (slot & 4);

    float inv = 1.0f / fmaxf(dn, 1e-20f);
    ushort4 o;
    o.x = f2b(t4[0] * inv); o.y = f2b(t4[1] * inv);
    o.z = f2b(t4[2] * inv); o.w = f2b(t4[3] * inv);
    *(ushort4*)(msg + (size_t)node * 256 + h * 32 + dimbase) = o;
}

// ---------- bf16 MFMA GEMM, BK=64, XOR-swizzled LDS (+ fused fine_bucket for MODE 1) ----
// blocks [0, fine_blocks): fine bucketing, one block per coarse bucket.
// blocks [fine_blocks, ...): GEMM C(M x Ntot) = A * Bt^T + bias.
// MODE 0: fp32 out. MODE 1: Q bf16 + fused KV8 fp8 rows.
template <int MODE>
__global__ __launch_bounds__(256) void gemm_bt_kernel(
    const u16* __restrict__ A, const u16* __restrict__ A2, int splitK,
    const u16* __restrict__ Bt, const float* __restrict__ bias,
    int M, int Ntot, int Ktot, int ntiles_n,
    float* __restrict__ outF, u16* __restrict__ outQ, u8* __restrict__ outKV,
    const uint2* __restrict__ ebuf, const int* __restrict__ cur,
    int* __restrict__ cnt, int* __restrict__ esrc, int fine_blocks) {
    __shared__ u16 As[128 * 64];
    __shared__ u16 Bs[128 * 64];
    if (MODE == 1 && (int)blockIdx.x < fine_blocks) {
        // fine bucketing: block cb owns nodes [cb*128, cb*128+128); cnt + esrc
        // regions touched by exactly one block -> L2-local, write-combines.
        int cb = blockIdx.x;
#pragma unroll 1
        for (int xp = 0; xp < 8; ++xp) {
            int sub = cb * 8 + xp;
            int n = cur[sub * 16];
            if (n > SUBCAP) n = SUBCAP;
            const uint2* base = ebuf + (size_t)sub * SUBCAP;
            for (int i = threadIdx.x; i < n; i += 256) {
                uint2 e = base[i];
                int dd = (int)e.y, ss = (int)e.x;
                int pos = atomicAdd(&cnt[dd], 1);
                if (pos < BUCKET) esrc[(size_t)dd * BUCKET + pos] = ss;
            }
        }
        return;
    }
    const int bid = blockIdx.x - (MODE == 1 ? fine_blocks : 0);
    const int tid = threadIdx.x;
    const int lane = tid & 63, wave = tid >> 6;
    const int wm = wave >> 1, wn = wave & 1;
    const int bm = bid / ntiles_n, bn = bid % ntiles_n;
    const int brow = bm * 128, bcol = bn * 128;

    f32x4 acc[4][4] = {};

    for (int k0 = 0; k0 < Ktot; k0 += 64) {
        const u16* Ab = (k0 < splitK) ? (A + k0) : (A2 + (k0 - splitK));
#pragma unroll
        for (int it = 0; it < 4; ++it) {
            int chunk = it * 256 + tid;          // 0..1023
            int row = chunk >> 3;                // 0..127
            int cg = chunk & 7;                  // 16B column-group
            int gcg = cg ^ (row & 7);            // inverse-swizzled global source
            int ga = brow + row; if (ga > M - 1) ga = M - 1;
            GLDS16(Ab + (size_t)ga * 256 + gcg * 8, As + (it * 256 + wave * 64) * 8);
            GLDS16(Bt + (size_t)(bcol + row) * Ktot + k0 + gcg * 8,
                   Bs + (it * 256 + wave * 64) * 8);
        }
        __syncthreads();
        const int kg = lane >> 4, rI = lane & 15, rx = lane & 7;
#pragma unroll
        for (int ks = 0; ks < 2; ++ks) {
            bf16x8 a[4], b[4];
#pragma unroll
            for (int m = 0; m < 4; ++m)
                a[m] = *(const bf16x8*)(As + (wm * 64 + m * 16 + rI) * 64 +
                                        (((ks * 4 + kg) ^ rx) * 8));
#pragma unroll
            for (int n = 0; n < 4; ++n)
                b[n] = *(const bf16x8*)(Bs + (wn * 64 + n * 16 + rI) * 64 +
                                        (((ks * 4 + kg) ^ rx) * 8));
#pragma unroll
            for (int m = 0; m < 4; ++m)
#pragma unroll
                for (int n = 0; n < 4; ++n)
                    acc[m][n] = __builtin_amdgcn_mfma_f32_16x16x32_bf16(a[m], b[n], acc[m][n], 0, 0, 0);
        }
        __syncthreads();
    }

#pragma unroll
    for (int m = 0; m < 4; ++m) {
        int growb = brow + wm * 64 + m * 16 + (lane >> 4) * 4;
#pragma unroll
        for (int n = 0; n < 4; ++n) {
            int gcol = bcol + wn * 64 + n * 16 + (lane & 15);
            float bi = bias[gcol];
#pragma unroll
            for (int r = 0; r < 4; ++r) {
                int grow = growb + r;
                if (grow >= M) continue;
                float c = acc[m][n][r] + bi;
                if (MODE == 0) {
                    outF[(size_t)grow * Ntot + gcol] = c;
                } else {
                    int hh = gcol / 96;
                    int rr = gcol - hh * 96;
                    int sel = rr >> 5;
                    int cc = hh * 32 + (rr & 31);
                    if (sel == 0) {
                        outQ[(size_t)grow * 256 + cc] = f2b(c);
                    } else {
                        unsigned pv = __builtin_amdgcn_cvt_pk_fp8_f32(c, c, 0, false);
                        outKV[(size_t)grow * 512 + (sel - 1) * 256 + cc] = (u8)(pv & 0xff);
                    }
                }
            }
        }
    }
}

extern "C" void kernel_launch(void* const* d_in, const int* in_sizes, int n_in,
                              void* d_out, int out_size, void* d_ws, size_t ws_size,
                              hipStream_t stream) {
    const float* x = (const float*)d_in[0];
    const float* W_qkv = (const float*)d_in[1];
    const float* b_qkv = (const float*)d_in[2];
    const float* W_out = (const float*)d_in[3];
    const float* b_out = (const float*)d_in[4];
    const int* src = (const int*)d_in[5];
    const int* dst = (const int*)d_in[6];
    float* out = (float*)d_out;

    char* w = (char*)d_ws;
    size_t off = 0;
    auto alloc = [&](size_t bytes) -> char* {
        char* p = w + off;
        off += (bytes + 255) & ~(size_t)255;
        return p;
    };
    u16* xb = (u16*)alloc((size_t)NN * 256 * 2);
    u16* WbT = (u16*)alloc((size_t)768 * 256 * 2);
    u16* WoT = (u16*)alloc((size_t)256 * 512 * 2);
    u16* Qb = (u16*)alloc((size_t)NN * 256 * 2);
    u8* KV8 = (u8*)alloc((size_t)NN * 512);
    u16* msg = Qb;  // alias: attn reads Q[node] fully into regs before writing msg[node]
    // cnt and cur contiguous -> single memset
    int* cnt = (int*)alloc((size_t)NN * 4 + (size_t)NB * 8 * 16 * 4);
    int* cur = cnt + NN;
    int* esrc = (int*)alloc((size_t)NN * BUCKET * 4);
    uint2* ebuf = (uint2*)alloc((size_t)NB * 8 * SUBCAP * 8);        // 38.4 MB
    // total workspace ~ 245 MB

    hipMemsetAsync(cnt, 0, (size_t)NN * 4 + (size_t)NB * 8 * 16 * 4, stream);

    // phase 1: coarse_scatter || cvt_x || transposes
    prep_kernel<<<PREP_BLOCKS, 256, 0, stream>>>(x, xb, W_qkv, WbT, W_out, WoT,
                                                 src, dst, cur, ebuf);

    // phase 2: fine_bucket (782 blocks) || QKV GEMM (4692 blocks)
    gemm_bt_kernel<1><<<NB + GEMM1_BLOCKS, 256, 0, stream>>>(
        xb, xb, 256, WbT, b_qkv, NN, 768, 256, 6,
        nullptr, Qb, KV8, ebuf, cur, cnt, esrc, NB);

    // phase 3: attention
    attn_kernel<<<NN / 4, 256, 0, stream>>>(Qb, KV8, cnt, esrc, msg);

    // phase 4: out = [xb | msg] @ W_out + b_out  (fp32 out)
    gemm_bt_kernel<0><<<782 * 2, 256, 0, stream>>>(
        xb, msg, 256, WoT, b_out, NN, 256, 512, 2,
        out, nullptr, nullptr, nullptr, nullptr, nullptr, nullptr, 0);
}

// Round 11
// 638.427 us; speedup vs baseline: 1.1927x; 1.0087x over previous
//
#include <hip/hip_runtime.h>
#include <hip/hip_bf16.h>

typedef unsigned short u16;
typedef unsigned char u8;
typedef short bf16x8 __attribute__((ext_vector_type(8)));
typedef float f32x4 __attribute__((ext_vector_type(4)));
typedef float f32x2 __attribute__((ext_vector_type(2)));

#define NN 100000
#define EE 3200000
#define BUCKET 128
#define NB 782          // coarse buckets: node>>7, 128 nodes each
#define SUBCAP 768      // capacity per (coarse, xcd) sub-bucket

#define COARSE_BLOCKS 3125   // EE/1024 edges, int4 per thread
#define CVT_BLOCKS 25000     // NN*256/4 float4 per thread
#define TR1_BLOCKS 768       // 256x768
#define TR2_BLOCKS 512       // 512x256
#define PREP_BLOCKS (COARSE_BLOCKS + CVT_BLOCKS + TR1_BLOCKS + TR2_BLOCKS)
#define GEMM1_BLOCKS (782 * 6)

static constexpr float COEF = 0.17677669529663687f; // 1/sqrt(32)

__device__ __forceinline__ u16 f2b(float f) {
    unsigned u = __float_as_uint(f);
    unsigned r = (u + 0x7fffu + ((u >> 16) & 1u)) >> 16;
    return (u16)r;
}

#define B2LO(w) __uint_as_float((w) << 16)
#define B2HI(w) __uint_as_float((w) & 0xffff0000u)

#define GLDS16(gp, lp) __builtin_amdgcn_global_load_lds( \
    (const __attribute__((address_space(1))) void*)(gp), \
    (__attribute__((address_space(3))) void*)(lp), 16, 0, 0)

// ---------- prep: coarse_scatter || cvt_x || transpose(W_qkv) || transpose(W_out) ----------
__global__ __launch_bounds__(256) void prep_kernel(
    const float* __restrict__ x, u16* __restrict__ xb,
    const float* __restrict__ Wq, u16* __restrict__ WbT,
    const float* __restrict__ Wo, u16* __restrict__ WoT,
    const int* __restrict__ src, const int* __restrict__ dst,
    int* __restrict__ cur, uint2* __restrict__ ebuf) {
    int b = blockIdx.x;
    int tid = threadIdx.x;
    if (b < COARSE_BLOCKS) {
        int e4 = b * 256 + tid;
        int xp = b & 7;
        int4 d = ((const int4*)dst)[e4];
        int4 s = ((const int4*)src)[e4];
        int sub0 = (d.x >> 7) * 8 + xp;
        int sub1 = (d.y >> 7) * 8 + xp;
        int sub2 = (d.z >> 7) * 8 + xp;
        int sub3 = (d.w >> 7) * 8 + xp;
        int p0 = atomicAdd(&cur[sub0 * 16], 1);   // cursors padded to 64B
        int p1 = atomicAdd(&cur[sub1 * 16], 1);
        int p2 = atomicAdd(&cur[sub2 * 16], 1);
        int p3 = atomicAdd(&cur[sub3 * 16], 1);
        if (p0 < SUBCAP) ebuf[(size_t)sub0 * SUBCAP + p0] = make_uint2((unsigned)s.x, (unsigned)d.x);
        if (p1 < SUBCAP) ebuf[(size_t)sub1 * SUBCAP + p1] = make_uint2((unsigned)s.y, (unsigned)d.y);
        if (p2 < SUBCAP) ebuf[(size_t)sub2 * SUBCAP + p2] = make_uint2((unsigned)s.z, (unsigned)d.z);
        if (p3 < SUBCAP) ebuf[(size_t)sub3 * SUBCAP + p3] = make_uint2((unsigned)s.w, (unsigned)d.w);
        return;
    }
    b -= COARSE_BLOCKS;
    if (b < CVT_BLOCKS) {
        int i = b * 256 + tid;
        float4 v = ((const float4*)x)[i];
        ushort4 o;
        o.x = f2b(v.x); o.y = f2b(v.y); o.z = f2b(v.z); o.w = f2b(v.w);
        ((ushort4*)xb)[i] = o;
        return;
    }
    b -= CVT_BLOCKS;
    if (b < TR1_BLOCKS) {
        int idx = b * 256 + tid;         // W_qkv: 256 x 768
        int r = idx / 768, c = idx - r * 768;
        WbT[(size_t)c * 256 + r] = f2b(Wq[idx]);
        return;
    }
    b -= TR1_BLOCKS;
    {
        int idx = b * 256 + tid;         // W_out: 512 x 256
        int r = idx >> 8, c = idx & 255;
        WoT[(size_t)c * 512 + r] = f2b(Wo[idx]);
    }
}

// ---------- per-node attention (node0 offset allows split dispatches) ----------
// h = lane>>3 (8 heads), slot = lane&7. Each lane processes 2 edges per iter.
// KV8: [node][512] bytes fp8 e4m3 — K bytes 0..255, V bytes 256..511.
__global__ __launch_bounds__(256) void attn_kernel(
    const u16* Q, const u8* __restrict__ KV8,
    const int* __restrict__ cnt, const int* __restrict__ esrc,
    u16* msg, int node0) {
    int node = node0 + blockIdx.x * 4 + (threadIdx.x >> 6);
    int lane = threadIdx.x & 63;
    int h = lane >> 3;
    int slot = lane & 7;
    int r0 = node * BUCKET;
    int r1 = r0 + min(cnt[node], BUCKET);

    f32x2 q2[16];
    {
        const uint4* qp = (const uint4*)(Q + (size_t)node * 256 + h * 32);
#pragma unroll
        for (int i = 0; i < 4; ++i) {
            uint4 wv = qp[i];
            q2[i * 4 + 0] = f32x2{B2LO(wv.x) * COEF, B2HI(wv.x) * COEF};
            q2[i * 4 + 1] = f32x2{B2LO(wv.y) * COEF, B2HI(wv.y) * COEF};
            q2[i * 4 + 2] = f32x2{B2LO(wv.z) * COEF, B2HI(wv.z) * COEF};
            q2[i * 4 + 3] = f32x2{B2LO(wv.w) * COEF, B2HI(wv.w) * COEF};
        }
    }

    float m = -3.0e38f, denom = 0.0f;
    f32x2 acc2[16];
#pragma unroll
    for (int i = 0; i < 16; ++i) acc2[i] = f32x2{0.0f, 0.0f};

#define DOTP(dd, u, j0) { f32x2 lo = __builtin_amdgcn_cvt_pk_f32_fp8(u, false); \
                          f32x2 hi = __builtin_amdgcn_cvt_pk_f32_fp8(u, true);  \
                          dd += q2[j0] * lo; dd += q2[(j0) + 1] * hi; }
#define ACCP(e2, u, j0) { f32x2 lo = __builtin_amdgcn_cvt_pk_f32_fp8(u, false); \
                          f32x2 hi = __builtin_amdgcn_cvt_pk_f32_fp8(u, true);  \
                          acc2[j0] += e2 * lo; acc2[(j0) + 1] += e2 * hi; }

    for (int base = r0; base < r1; base += 16) {
        int ja = base + slot, jb = base + 8 + slot;
        bool vA = ja < r1, vB = jb < r1;
        int sA = vA ? esrc[ja] : 0;
        int sB = vB ? esrc[jb] : 0;
        const uint4* pA = (const uint4*)(KV8 + (size_t)sA * 512 + h * 32);
        const uint4* pB = (const uint4*)(KV8 + (size_t)sB * 512 + h * 32);
        uint4 kA0 = pA[0], kA1 = pA[1], vA0 = pA[16], vA1 = pA[17];
        uint4 kB0 = pB[0], kB1 = pB[1], vB0 = pB[16], vB1 = pB[17];

        f32x2 dA2 = {0.0f, 0.0f}, dB2 = {0.0f, 0.0f};
        DOTP(dA2, kA0.x, 0);  DOTP(dA2, kA0.y, 2);  DOTP(dA2, kA0.z, 4);  DOTP(dA2, kA0.w, 6);
        DOTP(dA2, kA1.x, 8);  DOTP(dA2, kA1.y, 10); DOTP(dA2, kA1.z, 12); DOTP(dA2, kA1.w, 14);
        DOTP(dB2, kB0.x, 0);  DOTP(dB2, kB0.y, 2);  DOTP(dB2, kB0.z, 4);  DOTP(dB2, kB0.w, 6);
        DOTP(dB2, kB1.x, 8);  DOTP(dB2, kB1.y, 10); DOTP(dB2, kB1.z, 12); DOTP(dB2, kB1.w, 14);
        float dA = vA ? (dA2[0] + dA2[1]) : -3.0e38f;
        float dB = vB ? (dB2[0] + dB2[1]) : -3.0e38f;

        float dm = fmaxf(dA, dB);
        if (dm > m + 4.0f) {                // defer-max: rescale only on big growth
            float scale = __expf(m - dm);
            m = dm;
            denom *= scale;
            f32x2 s2 = {scale, scale};
#pragma unroll
            for (int i = 0; i < 16; ++i) acc2[i] *= s2;
        }
        float exA = vA ? __expf(dA - m) : 0.0f;   // bounded by e^4
        float exB = vB ? __expf(dB - m) : 0.0f;
        denom += exA + exB;
        f32x2 eA2 = {exA, exA}, eB2 = {exB, exB};
        ACCP(eA2, vA0.x, 0);  ACCP(eA2, vA0.y, 2);  ACCP(eA2, vA0.z, 4);  ACCP(eA2, vA0.w, 6);
        ACCP(eA2, vA1.x, 8);  ACCP(eA2, vA1.y, 10); ACCP(eA2, vA1.z, 12); ACCP(eA2, vA1.w, 14);
        ACCP(eB2, vB0.x, 0);  ACCP(eB2, vB0.y, 2);  ACCP(eB2, vB0.z, 4);  ACCP(eB2, vB0.w, 6);
        ACCP(eB2, vB1.x, 8);  ACCP(eB2, vB1.y, 10); ACCP(eB2, vB1.z, 12); ACCP(eB2, vB1.w, 14);
    }

    // ---- per-node merge across the 8 slots ----
    float mg = fmaxf(m, __shfl_xor(m, 1));
    mg = fmaxf(mg, __shfl_xor(mg, 2));
    mg = fmaxf(mg, __shfl_xor(mg, 4));
    float f = __expf(m - mg);
    float dn = denom * f;
    dn += __shfl_xor(dn, 1);
    dn += __shfl_xor(dn, 2);
    dn += __shfl_xor(dn, 4);
    float acc[32];
#pragma unroll
    for (int i = 0; i < 16; ++i) {
        acc[2 * i] = acc2[i][0] * f;
        acc[2 * i + 1] = acc2[i][1] * f;
    }

    float t16[16];
#pragma unroll
    for (int i = 0; i < 16; ++i) {
        float send = (slot & 1) ? acc[i] : acc[i + 16];
        float recv = __shfl_xor(send, 1);
        t16[i] = ((slot & 1) ? acc[i + 16] : acc[i]) + recv;
    }
    float t8[8];
#pragma unroll
    for (int i = 0; i < 8; ++i) {
        float send = (slot & 2) ? t16[i] : t16[i + 8];
        float recv = __shfl_xor(send, 2);
        t8[i] = ((slot & 2) ? t16[i + 8] : t16[i]) + recv;
    }
    float t4[4];
#pragma unroll
    for (int i = 0; i < 4; ++i) {
        float send = (slot & 4) ? t8[i] : t8[i + 4];
        float recv = __shfl_xor(send, 4);
        t4[i] = ((slot & 4) ? t8[i + 4] : t8[i]) + recv;
    }
    int dimbase = ((slot & 1) << 4) | ((slot & 2) << 2) | (slot & 4);

    float inv = 1.0f / fmaxf(dn, 1e-20f);
    ushort4 o;
    o.x = f2b(t4[0] * inv); o.y = f2b(t4[1] * inv);
    o.z = f2b(t4[2] * inv); o.w = f2b(t4[3] * inv);
    *(ushort4*)(msg + (size_t)node * 256 + h * 32 + dimbase) = o;
}

// ---------- bf16 MFMA GEMM, BK=64, XOR-swizzled LDS, XCD-bijective tile swizzle ----------
// blocks [0, fine_blocks) in MODE 1: fine bucketing. Rest: GEMM tiles.
// Tile swizzle (m204 bijective): bid%8 ~ physical XCD (round-robin dispatch);
// each XCD gets a CONTIGUOUS tile range -> consecutive bn share the A-panel in
// that XCD's L2 (A re-reads served from L2 instead of L3).
template <int MODE>
__global__ __launch_bounds__(256) void gemm_bt_kernel(
    const u16* __restrict__ A, const u16* __restrict__ A2, int splitK,
    const u16* __restrict__ Bt, const float* __restrict__ bias,
    int M, int Ntot, int Ktot, int ntiles_n, int nwg,
    float* __restrict__ outF, u16* __restrict__ outQ, u8* __restrict__ outKV,
    const uint2* __restrict__ ebuf, const int* __restrict__ cur,
    int* __restrict__ cnt, int* __restrict__ esrc, int fine_blocks) {
    __shared__ u16 As[128 * 64];
    __shared__ u16 Bs[128 * 64];
    if (MODE == 1 && (int)blockIdx.x < fine_blocks) {
        int cb = blockIdx.x;
#pragma unroll 1
        for (int xp = 0; xp < 8; ++xp) {
            int sub = cb * 8 + xp;
            int n = cur[sub * 16];
            if (n > SUBCAP) n = SUBCAP;
            const uint2* base = ebuf + (size_t)sub * SUBCAP;
            for (int i = threadIdx.x; i < n; i += 256) {
                uint2 e = base[i];
                int dd = (int)e.y, ss = (int)e.x;
                int pos = atomicAdd(&cnt[dd], 1);
                if (pos < BUCKET) esrc[(size_t)dd * BUCKET + pos] = ss;
            }
        }
        return;
    }
    const int bid = blockIdx.x - (MODE == 1 ? fine_blocks : 0);
    // m204 bijective XCD swizzle: xcd = bid&7 (constant shift vs physical XCD)
    const int qq = nwg >> 3, rr = nwg & 7;
    const int xcd = bid & 7;
    const int tile = (xcd < rr ? xcd * (qq + 1) : rr * (qq + 1) + (xcd - rr) * qq) + (bid >> 3);
    const int tid = threadIdx.x;
    const int lane = tid & 63, wave = tid >> 6;
    const int wm = wave >> 1, wn = wave & 1;
    const int bm = tile / ntiles_n, bn = tile % ntiles_n;
    const int brow = bm * 128, bcol = bn * 128;

    f32x4 acc[4][4] = {};

    for (int k0 = 0; k0 < Ktot; k0 += 64) {
        const u16* Ab = (k0 < splitK) ? (A + k0) : (A2 + (k0 - splitK));
#pragma unroll
        for (int it = 0; it < 4; ++it) {
            int chunk = it * 256 + tid;          // 0..1023
            int row = chunk >> 3;                // 0..127
            int cg = chunk & 7;                  // 16B column-group
            int gcg = cg ^ (row & 7);            // inverse-swizzled global source
            int ga = brow + row; if (ga > M - 1) ga = M - 1;
            GLDS16(Ab + (size_t)ga * 256 + gcg * 8, As + (it * 256 + wave * 64) * 8);
            GLDS16(Bt + (size_t)(bcol + row) * Ktot + k0 + gcg * 8,
                   Bs + (it * 256 + wave * 64) * 8);
        }
        __syncthreads();
        const int kg = lane >> 4, rI = lane & 15, rx = lane & 7;
#pragma unroll
        for (int ks = 0; ks < 2; ++ks) {
            bf16x8 a[4], b[4];
#pragma unroll
            for (int m = 0; m < 4; ++m)
                a[m] = *(const bf16x8*)(As + (wm * 64 + m * 16 + rI) * 64 +
                                        (((ks * 4 + kg) ^ rx) * 8));
#pragma unroll
            for (int n = 0; n < 4; ++n)
                b[n] = *(const bf16x8*)(Bs + (wn * 64 + n * 16 + rI) * 64 +
                                        (((ks * 4 + kg) ^ rx) * 8));
#pragma unroll
            for (int m = 0; m < 4; ++m)
#pragma unroll
                for (int n = 0; n < 4; ++n)
                    acc[m][n] = __builtin_amdgcn_mfma_f32_16x16x32_bf16(a[m], b[n], acc[m][n], 0, 0, 0);
        }
        __syncthreads();
    }

#pragma unroll
    for (int m = 0; m < 4; ++m) {
        int growb = brow + wm * 64 + m * 16 + (lane >> 4) * 4;
#pragma unroll
        for (int n = 0; n < 4; ++n) {
            int gcol = bcol + wn * 64 + n * 16 + (lane & 15);
            float bi = bias[gcol];
#pragma unroll
            for (int r = 0; r < 4; ++r) {
                int grow = growb + r;
                if (grow >= M) continue;
                float c = acc[m][n][r] + bi;
                if (MODE == 0) {
                    outF[(size_t)grow * Ntot + gcol] = c;
                } else {
                    int hh = gcol / 96;
                    int rrm = gcol - hh * 96;
                    int sel = rrm >> 5;
                    int cc = hh * 32 + (rrm & 31);
                    if (sel == 0) {
                        outQ[(size_t)grow * 256 + cc] = f2b(c);
                    } else {
                        unsigned pv = __builtin_amdgcn_cvt_pk_fp8_f32(c, c, 0, false);
                        outKV[(size_t)grow * 512 + (sel - 1) * 256 + cc] = (u8)(pv & 0xff);
                    }
                }
            }
        }
    }
}

extern "C" void kernel_launch(void* const* d_in, const int* in_sizes, int n_in,
                              void* d_out, int out_size, void* d_ws, size_t ws_size,
                              hipStream_t stream) {
    const float* x = (const float*)d_in[0];
    const float* W_qkv = (const float*)d_in[1];
    const float* b_qkv = (const float*)d_in[2];
    const float* W_out = (const float*)d_in[3];
    const float* b_out = (const float*)d_in[4];
    const int* src = (const int*)d_in[5];
    const int* dst = (const int*)d_in[6];
    float* out = (float*)d_out;

    char* w = (char*)d_ws;
    size_t off = 0;
    auto alloc = [&](size_t bytes) -> char* {
        char* p = w + off;
        off += (bytes + 255) & ~(size_t)255;
        return p;
    };
    u16* xb = (u16*)alloc((size_t)NN * 256 * 2);
    u16* WbT = (u16*)alloc((size_t)768 * 256 * 2);
    u16* WoT = (u16*)alloc((size_t)256 * 512 * 2);
    u16* Qb = (u16*)alloc((size_t)NN * 256 * 2);
    u8* KV8 = (u8*)alloc((size_t)NN * 512);
    u16* msg = Qb;  // alias: attn reads Q[node] fully into regs before writing msg[node]
    int* cnt = (int*)alloc((size_t)NN * 4 + (size_t)NB * 8 * 16 * 4);
    int* cur = cnt + NN;
    int* esrc = (int*)alloc((size_t)NN * BUCKET * 4);
    uint2* ebuf = (uint2*)alloc((size_t)NB * 8 * SUBCAP * 8);        // 38.4 MB
    // total workspace ~ 245 MB

    hipMemsetAsync(cnt, 0, (size_t)NN * 4 + (size_t)NB * 8 * 16 * 4, stream);

    // phase 1: coarse_scatter || cvt_x || transposes
    prep_kernel<<<PREP_BLOCKS, 256, 0, stream>>>(x, xb, W_qkv, WbT, W_out, WoT,
                                                 src, dst, cur, ebuf);

    // phase 2: fine_bucket (782 blocks) || QKV GEMM (4692 blocks)
    gemm_bt_kernel<1><<<NB + GEMM1_BLOCKS, 256, 0, stream>>>(
        xb, xb, 256, WbT, b_qkv, NN, 768, 256, 6, GEMM1_BLOCKS,
        nullptr, Qb, KV8, ebuf, cur, cnt, esrc, NB);

    // phase 3: attention (split in two for profile visibility)
    attn_kernel<<<NN / 8, 256, 0, stream>>>(Qb, KV8, cnt, esrc, msg, 0);
    attn_kernel<<<NN / 8, 256, 0, stream>>>(Qb, KV8, cnt, esrc, msg, NN / 2);

    // phase 4: out = [xb | msg] @ W_out + b_out  (fp32 out)
    gemm_bt_kernel<0><<<782 * 2, 256, 0, stream>>>(
        xb, msg, 256, WoT, b_out, NN, 256, 512, 2, 782 * 2,
        out, nullptr, nullptr, nullptr, nullptr, nullptr, nullptr, 0);
}

// Round 12
// 496.878 us; speedup vs baseline: 1.5325x; 1.2849x over previous
//
#include <hip/hip_runtime.h>
#include <hip/hip_bf16.h>

typedef unsigned short u16;
typedef unsigned char u8;
typedef short bf16x8 __attribute__((ext_vector_type(8)));
typedef float f32x4 __attribute__((ext_vector_type(4)));
typedef float f32x2 __attribute__((ext_vector_type(2)));

#define NN 100000
#define EE 3200000
#define BUCKET 128
#define NCB 98          // coarse buckets: node>>10, 1024 nodes each
#define SUBCAP 4608     // capacity per (coarse, xcd) sub-bucket; mean ~4100, ~8 sigma

#define COARSE_BLOCKS 3125   // EE/1024 edges, int4 per thread
#define CVT_BLOCKS 25000     // NN*256/4 float4 per thread
#define TR1_BLOCKS 768       // 256x768
#define TR2_BLOCKS 512       // 512x256
#define PREP_BLOCKS (COARSE_BLOCKS + CVT_BLOCKS + TR1_BLOCKS + TR2_BLOCKS)
#define GEMM1_BLOCKS (782 * 6)

static constexpr float COEF = 0.17677669529663687f; // 1/sqrt(32)

__device__ __forceinline__ u16 f2b(float f) {
    unsigned u = __float_as_uint(f);
    unsigned r = (u + 0x7fffu + ((u >> 16) & 1u)) >> 16;
    return (u16)r;
}

#define B2LO(w) __uint_as_float((w) << 16)
#define B2HI(w) __uint_as_float((w) & 0xffff0000u)

#define GLDS16(gp, lp) __builtin_amdgcn_global_load_lds( \
    (const __attribute__((address_space(1))) void*)(gp), \
    (__attribute__((address_space(3))) void*)(lp), 16, 0, 0)

// ---------- prep: coarse_scatter || cvt_x || transpose(W_qkv) || transpose(W_out) ----------
// Coarse scatter is LDS-aggregated: per block, count edges per coarse bucket in LDS,
// reserve ranges with ONE device atomic per touched bucket (~98/block instead of 1024),
// then write 8B records at base+local_pos -> ~84B contiguous runs, write-combining.
__global__ __launch_bounds__(256) void prep_kernel(
    const float* __restrict__ x, u16* __restrict__ xb,
    const float* __restrict__ Wq, u16* __restrict__ WbT,
    const float* __restrict__ Wo, u16* __restrict__ WoT,
    const int* __restrict__ src, const int* __restrict__ dst,
    int* __restrict__ cur, uint2* __restrict__ ebuf) {
    __shared__ int lcnt[NCB];
    __shared__ int lbase[NCB];
    int b = blockIdx.x;
    int tid = threadIdx.x;
    if (b < COARSE_BLOCKS) {
        int e4 = b * 256 + tid;
        int xp = b & 7;                       // ~XCD (round-robin dispatch)
        int4 d = ((const int4*)dst)[e4];
        int4 s = ((const int4*)src)[e4];
        int cb0 = d.x >> 10, cb1 = d.y >> 10, cb2 = d.z >> 10, cb3 = d.w >> 10;
        if (tid < NCB) lcnt[tid] = 0;
        __syncthreads();
        int l0 = atomicAdd(&lcnt[cb0], 1);    // LDS atomics: intra-CU, fast
        int l1 = atomicAdd(&lcnt[cb1], 1);
        int l2 = atomicAdd(&lcnt[cb2], 1);
        int l3 = atomicAdd(&lcnt[cb3], 1);
        __syncthreads();
        if (tid < NCB) {
            int c = lcnt[tid];
            lbase[tid] = c ? atomicAdd(&cur[(tid * 8 + xp) * 16], c) : 0;
        }
        __syncthreads();
        int p0 = lbase[cb0] + l0, p1 = lbase[cb1] + l1;
        int p2 = lbase[cb2] + l2, p3 = lbase[cb3] + l3;
        if (p0 < SUBCAP) ebuf[(size_t)(cb0 * 8 + xp) * SUBCAP + p0] = make_uint2((unsigned)s.x, (unsigned)d.x);
        if (p1 < SUBCAP) ebuf[(size_t)(cb1 * 8 + xp) * SUBCAP + p1] = make_uint2((unsigned)s.y, (unsigned)d.y);
        if (p2 < SUBCAP) ebuf[(size_t)(cb2 * 8 + xp) * SUBCAP + p2] = make_uint2((unsigned)s.z, (unsigned)d.z);
        if (p3 < SUBCAP) ebuf[(size_t)(cb3 * 8 + xp) * SUBCAP + p3] = make_uint2((unsigned)s.w, (unsigned)d.w);
        return;
    }
    b -= COARSE_BLOCKS;
    if (b < CVT_BLOCKS) {
        int i = b * 256 + tid;
        float4 v = ((const float4*)x)[i];
        ushort4 o;
        o.x = f2b(v.x); o.y = f2b(v.y); o.z = f2b(v.z); o.w = f2b(v.w);
        ((ushort4*)xb)[i] = o;
        return;
    }
    b -= CVT_BLOCKS;
    if (b < TR1_BLOCKS) {
        int idx = b * 256 + tid;         // W_qkv: 256 x 768
        int r = idx / 768, c = idx - r * 768;
        WbT[(size_t)c * 256 + r] = f2b(Wq[idx]);
        return;
    }
    b -= TR1_BLOCKS;
    {
        int idx = b * 256 + tid;         // W_out: 512 x 256
        int r = idx >> 8, c = idx & 255;
        WoT[(size_t)c * 512 + r] = f2b(Wo[idx]);
    }
}

// ---------- per-node attention (node0 offset allows split dispatches) ----------
// h = lane>>3 (8 heads), slot = lane&7. Each lane processes 2 edges per iter.
// KV8: [node][512] bytes fp8 e4m3 — K bytes 0..255, V bytes 256..511.
__global__ __launch_bounds__(256) void attn_kernel(
    const u16* Q, const u8* __restrict__ KV8,
    const int* __restrict__ cnt, const int* __restrict__ esrc,
    u16* msg, int node0) {
    int node = node0 + blockIdx.x * 4 + (threadIdx.x >> 6);
    int lane = threadIdx.x & 63;
    int h = lane >> 3;
    int slot = lane & 7;
    int r0 = node * BUCKET;
    int r1 = r0 + min(cnt[node], BUCKET);

    f32x2 q2[16];
    {
        const uint4* qp = (const uint4*)(Q + (size_t)node * 256 + h * 32);
#pragma unroll
        for (int i = 0; i < 4; ++i) {
            uint4 wv = qp[i];
            q2[i * 4 + 0] = f32x2{B2LO(wv.x) * COEF, B2HI(wv.x) * COEF};
            q2[i * 4 + 1] = f32x2{B2LO(wv.y) * COEF, B2HI(wv.y) * COEF};
            q2[i * 4 + 2] = f32x2{B2LO(wv.z) * COEF, B2HI(wv.z) * COEF};
            q2[i * 4 + 3] = f32x2{B2LO(wv.w) * COEF, B2HI(wv.w) * COEF};
        }
    }

    float m = -3.0e38f, denom = 0.0f;
    f32x2 acc2[16];
#pragma unroll
    for (int i = 0; i < 16; ++i) acc2[i] = f32x2{0.0f, 0.0f};

#define DOTP(dd, u, j0) { f32x2 lo = __builtin_amdgcn_cvt_pk_f32_fp8(u, false); \
                          f32x2 hi = __builtin_amdgcn_cvt_pk_f32_fp8(u, true);  \
                          dd += q2[j0] * lo; dd += q2[(j0) + 1] * hi; }
#define ACCP(e2, u, j0) { f32x2 lo = __builtin_amdgcn_cvt_pk_f32_fp8(u, false); \
                          f32x2 hi = __builtin_amdgcn_cvt_pk_f32_fp8(u, true);  \
                          acc2[j0] += e2 * lo; acc2[(j0) + 1] += e2 * hi; }

    for (int base = r0; base < r1; base += 16) {
        int ja = base + slot, jb = base + 8 + slot;
        bool vA = ja < r1, vB = jb < r1;
        int sA = vA ? esrc[ja] : 0;
        int sB = vB ? esrc[jb] : 0;
        const uint4* pA = (const uint4*)(KV8 + (size_t)sA * 512 + h * 32);
        const uint4* pB = (const uint4*)(KV8 + (size_t)sB * 512 + h * 32);
        uint4 kA0 = pA[0], kA1 = pA[1], vA0 = pA[16], vA1 = pA[17];
        uint4 kB0 = pB[0], kB1 = pB[1], vB0 = pB[16], vB1 = pB[17];

        f32x2 dA2 = {0.0f, 0.0f}, dB2 = {0.0f, 0.0f};
        DOTP(dA2, kA0.x, 0);  DOTP(dA2, kA0.y, 2);  DOTP(dA2, kA0.z, 4);  DOTP(dA2, kA0.w, 6);
        DOTP(dA2, kA1.x, 8);  DOTP(dA2, kA1.y, 10); DOTP(dA2, kA1.z, 12); DOTP(dA2, kA1.w, 14);
        DOTP(dB2, kB0.x, 0);  DOTP(dB2, kB0.y, 2);  DOTP(dB2, kB0.z, 4);  DOTP(dB2, kB0.w, 6);
        DOTP(dB2, kB1.x, 8);  DOTP(dB2, kB1.y, 10); DOTP(dB2, kB1.z, 12); DOTP(dB2, kB1.w, 14);
        float dA = vA ? (dA2[0] + dA2[1]) : -3.0e38f;
        float dB = vB ? (dB2[0] + dB2[1]) : -3.0e38f;

        float dm = fmaxf(dA, dB);
        if (dm > m + 4.0f) {                // defer-max: rescale only on big growth
            float scale = __expf(m - dm);
            m = dm;
            denom *= scale;
            f32x2 s2 = {scale, scale};
#pragma unroll
            for (int i = 0; i < 16; ++i) acc2[i] *= s2;
        }
        float exA = vA ? __expf(dA - m) : 0.0f;   // bounded by e^4
        float exB = vB ? __expf(dB - m) : 0.0f;
        denom += exA + exB;
        f32x2 eA2 = {exA, exA}, eB2 = {exB, exB};
        ACCP(eA2, vA0.x, 0);  ACCP(eA2, vA0.y, 2);  ACCP(eA2, vA0.z, 4);  ACCP(eA2, vA0.w, 6);
        ACCP(eA2, vA1.x, 8);  ACCP(eA2, vA1.y, 10); ACCP(eA2, vA1.z, 12); ACCP(eA2, vA1.w, 14);
        ACCP(eB2, vB0.x, 0);  ACCP(eB2, vB0.y, 2);  ACCP(eB2, vB0.z, 4);  ACCP(eB2, vB0.w, 6);
        ACCP(eB2, vB1.x, 8);  ACCP(eB2, vB1.y, 10); ACCP(eB2, vB1.z, 12); ACCP(eB2, vB1.w, 14);
    }

    // ---- per-node merge across the 8 slots ----
    float mg = fmaxf(m, __shfl_xor(m, 1));
    mg = fmaxf(mg, __shfl_xor(mg, 2));
    mg = fmaxf(mg, __shfl_xor(mg, 4));
    float f = __expf(m - mg);
    float dn = denom * f;
    dn += __shfl_xor(dn, 1);
    dn += __shfl_xor(dn, 2);
    dn += __shfl_xor(dn, 4);
    float acc[32];
#pragma unroll
    for (int i = 0; i < 16; ++i) {
        acc[2 * i] = acc2[i][0] * f;
        acc[2 * i + 1] = acc2[i][1] * f;
    }

    float t16[16];
#pragma unroll
    for (int i = 0; i < 16; ++i) {
        float send = (slot & 1) ? acc[i] : acc[i + 16];
        float recv = __shfl_xor(send, 1);
        t16[i] = ((slot & 1) ? acc[i + 16] : acc[i]) + recv;
    }
    float t8[8];
#pragma unroll
    for (int i = 0; i < 8; ++i) {
        float send = (slot & 2) ? t16[i] : t16[i + 8];
        float recv = __shfl_xor(send, 2);
        t8[i] = ((slot & 2) ? t16[i + 8] : t16[i]) + recv;
    }
    float t4[4];
#pragma unroll
    for (int i = 0; i < 4; ++i) {
        float send = (slot & 4) ? t8[i] : t8[i + 4];
        float recv = __shfl_xor(send, 4);
        t4[i] = ((slot & 4) ? t8[i + 4] : t8[i]) + recv;
    }
    int dimbase = ((slot & 1) << 4) | ((slot & 2) << 2) | (slot & 4);

    float inv = 1.0f / fmaxf(dn, 1e-20f);
    ushort4 o;
    o.x = f2b(t4[0] * inv); o.y = f2b(t4[1] * inv);
    o.z = f2b(t4[2] * inv); o.w = f2b(t4[3] * inv);
    *(ushort4*)(msg + (size_t)node * 256 + h * 32 + dimbase) = o;
}

// ---------- bf16 MFMA GEMM, BK=64, XOR-swizzled LDS, XCD-bijective tile swizzle ----------
// MODE 1 blocks [0, fine_blocks): fine bucketing with LDS counters (no device atomics);
// block cb owns nodes [cb*1024, cb*1024+1024), writes cnt[] directly at the end.
template <int MODE>
__global__ __launch_bounds__(256) void gemm_bt_kernel(
    const u16* __restrict__ A, const u16* __restrict__ A2, int splitK,
    const u16* __restrict__ Bt, const float* __restrict__ bias,
    int M, int Ntot, int Ktot, int ntiles_n, int nwg,
    float* __restrict__ outF, u16* __restrict__ outQ, u8* __restrict__ outKV,
    const uint2* __restrict__ ebuf, const int* __restrict__ cur,
    int* __restrict__ cnt, int* __restrict__ esrc, int fine_blocks) {
    __shared__ u16 As[128 * 64];
    __shared__ u16 Bs[128 * 64];
    if (MODE == 1 && (int)blockIdx.x < fine_blocks) {
        int cb = blockIdx.x;
        int nodebase = cb << 10;
        int* lcnt = (int*)As;            // reuse GEMM LDS: 1024 ints
        for (int i = threadIdx.x; i < 1024; i += 256) lcnt[i] = 0;
        __syncthreads();
#pragma unroll 1
        for (int xp = 0; xp < 8; ++xp) {
            int sub = cb * 8 + xp;
            int n = cur[sub * 16];
            if (n > SUBCAP) n = SUBCAP;
            const uint2* base = ebuf + (size_t)sub * SUBCAP;
            for (int i = threadIdx.x; i < n; i += 256) {
                uint2 e = base[i];
                int dd = (int)e.y;
                int pos = atomicAdd(&lcnt[dd - nodebase], 1);   // LDS atomic
                if (pos < BUCKET) esrc[(size_t)dd * BUCKET + pos] = (int)e.x;
            }
        }
        __syncthreads();
        for (int i = threadIdx.x; i < 1024; i += 256) {
            int nd = nodebase + i;
            if (nd < NN) cnt[nd] = min(lcnt[i], BUCKET);
        }
        return;
    }
    const int bid = blockIdx.x - (MODE == 1 ? fine_blocks : 0);
    // m204 bijective XCD swizzle: each XCD gets a contiguous tile range
    const int qq = nwg >> 3, rr = nwg & 7;
    const int xcd = bid & 7;
    const int tile = (xcd < rr ? xcd * (qq + 1) : rr * (qq + 1) + (xcd - rr) * qq) + (bid >> 3);
    const int tid = threadIdx.x;
    const int lane = tid & 63, wave = tid >> 6;
    const int wm = wave >> 1, wn = wave & 1;
    const int bm = tile / ntiles_n, bn = tile % ntiles_n;
    const int brow = bm * 128, bcol = bn * 128;

    f32x4 acc[4][4] = {};

    for (int k0 = 0; k0 < Ktot; k0 += 64) {
        const u16* Ab = (k0 < splitK) ? (A + k0) : (A2 + (k0 - splitK));
#pragma unroll
        for (int it = 0; it < 4; ++it) {
            int chunk = it * 256 + tid;          // 0..1023
            int row = chunk >> 3;                // 0..127
            int cg = chunk & 7;                  // 16B column-group
            int gcg = cg ^ (row & 7);            // inverse-swizzled global source
            int ga = brow + row; if (ga > M - 1) ga = M - 1;
            GLDS16(Ab + (size_t)ga * 256 + gcg * 8, As + (it * 256 + wave * 64) * 8);
            GLDS16(Bt + (size_t)(bcol + row) * Ktot + k0 + gcg * 8,
                   Bs + (it * 256 + wave * 64) * 8);
        }
        __syncthreads();
        const int kg = lane >> 4, rI = lane & 15, rx = lane & 7;
#pragma unroll
        for (int ks = 0; ks < 2; ++ks) {
            bf16x8 a[4], b[4];
#pragma unroll
            for (int m = 0; m < 4; ++m)
                a[m] = *(const bf16x8*)(As + (wm * 64 + m * 16 + rI) * 64 +
                                        (((ks * 4 + kg) ^ rx) * 8));
#pragma unroll
            for (int n = 0; n < 4; ++n)
                b[n] = *(const bf16x8*)(Bs + (wn * 64 + n * 16 + rI) * 64 +
                                        (((ks * 4 + kg) ^ rx) * 8));
#pragma unroll
            for (int m = 0; m < 4; ++m)
#pragma unroll
                for (int n = 0; n < 4; ++n)
                    acc[m][n] = __builtin_amdgcn_mfma_f32_16x16x32_bf16(a[m], b[n], acc[m][n], 0, 0, 0);
        }
        __syncthreads();
    }

#pragma unroll
    for (int m = 0; m < 4; ++m) {
        int growb = brow + wm * 64 + m * 16 + (lane >> 4) * 4;
#pragma unroll
        for (int n = 0; n < 4; ++n) {
            int gcol = bcol + wn * 64 + n * 16 + (lane & 15);
            float bi = bias[gcol];
#pragma unroll
            for (int r = 0; r < 4; ++r) {
                int grow = growb + r;
                if (grow >= M) continue;
                float c = acc[m][n][r] + bi;
                if (MODE == 0) {
                    outF[(size_t)grow * Ntot + gcol] = c;
                } else {
                    int hh = gcol / 96;
                    int rrm = gcol - hh * 96;
                    int sel = rrm >> 5;
                    int cc = hh * 32 + (rrm & 31);
                    if (sel == 0) {
                        outQ[(size_t)grow * 256 + cc] = f2b(c);
                    } else {
                        unsigned pv = __builtin_amdgcn_cvt_pk_fp8_f32(c, c, 0, false);
                        outKV[(size_t)grow * 512 + (sel - 1) * 256 + cc] = (u8)(pv & 0xff);
                    }
                }
            }
        }
    }
}

extern "C" void kernel_launch(void* const* d_in, const int* in_sizes, int n_in,
                              void* d_out, int out_size, void* d_ws, size_t ws_size,
                              hipStream_t stream) {
    const float* x = (const float*)d_in[0];
    const float* W_qkv = (const float*)d_in[1];
    const float* b_qkv = (const float*)d_in[2];
    const float* W_out = (const float*)d_in[3];
    const float* b_out = (const float*)d_in[4];
    const int* src = (const int*)d_in[5];
    const int* dst = (const int*)d_in[6];
    float* out = (float*)d_out;

    char* w = (char*)d_ws;
    size_t off = 0;
    auto alloc = [&](size_t bytes) -> char* {
        char* p = w + off;
        off += (bytes + 255) & ~(size_t)255;
        return p;
    };
    u16* xb = (u16*)alloc((size_t)NN * 256 * 2);
    u16* WbT = (u16*)alloc((size_t)768 * 256 * 2);
    u16* WoT = (u16*)alloc((size_t)256 * 512 * 2);
    u16* Qb = (u16*)alloc((size_t)NN * 256 * 2);
    u8* KV8 = (u8*)alloc((size_t)NN * 512);
    u16* msg = Qb;  // alias: attn reads Q[node] fully into regs before writing msg[node]
    int* cnt = (int*)alloc((size_t)NN * 4);                          // written by fine (no memset)
    int* cur = (int*)alloc((size_t)NCB * 8 * 16 * 4);                // padded cursors, 50 KB
    int* esrc = (int*)alloc((size_t)NN * BUCKET * 4);
    uint2* ebuf = (uint2*)alloc((size_t)NCB * 8 * SUBCAP * 8);       // 28.9 MB
    // total workspace ~ 235 MB

    hipMemsetAsync(cur, 0, (size_t)NCB * 8 * 16 * 4, stream);

    // phase 1: coarse_scatter (LDS-aggregated) || cvt_x || transposes
    prep_kernel<<<PREP_BLOCKS, 256, 0, stream>>>(x, xb, W_qkv, WbT, W_out, WoT,
                                                 src, dst, cur, ebuf);

    // phase 2: fine_bucket (98 blocks, LDS counters) || QKV GEMM (4692 blocks)
    gemm_bt_kernel<1><<<NCB + GEMM1_BLOCKS, 256, 0, stream>>>(
        xb, xb, 256, WbT, b_qkv, NN, 768, 256, 6, GEMM1_BLOCKS,
        nullptr, Qb, KV8, ebuf, cur, cnt, esrc, NCB);

    // phase 3: attention (split in two for profile visibility)
    attn_kernel<<<NN / 8, 256, 0, stream>>>(Qb, KV8, cnt, esrc, msg, 0);
    attn_kernel<<<NN / 8, 256, 0, stream>>>(Qb, KV8, cnt, esrc, msg, NN / 2);

    // phase 4: out = [xb | msg] @ W_out + b_out  (fp32 out)
    gemm_bt_kernel<0><<<782 * 2, 256, 0, stream>>>(
        xb, msg, 256, WoT, b_out, NN, 256, 512, 2, 782 * 2,
        out, nullptr, nullptr, nullptr, nullptr, nullptr, nullptr, 0);
}